// Round 7
// baseline (6524.014 us; speedup 1.0000x reference)
//
#include <hip/hip_runtime.h>
#include <stdint.h>

// Problem constants
#define B_     2
#define T_     4096
#define NB_    4
#define D_     512
#define E_     4096
#define NE_    16384           // NB*E
#define HALF_  67108864u       // T*NB*E  (per-b flat block of [B,T,NB,E])
#define SLOTS_ 32768           // B*T*NB

typedef unsigned long long u64;
typedef uint32_t u32;

// ---------------- Threefry-2x32-20, key = (0, 42) ----------------
__device__ __forceinline__ u32 rotl32(u32 x, int r) { return (x << r) | (x >> (32 - r)); }

__device__ __forceinline__ void tf_0_42(u32 x0, u32 x1, u32 &o0, u32 &o1) {
  const u32 ks0 = 0u, ks1 = 42u, ks2 = 0x1BD11BDAu ^ 0u ^ 42u;
  x0 += ks0; x1 += ks1;
#define TFR(r) { x0 += x1; x1 = rotl32(x1, (r)); x1 ^= x0; }
  TFR(13) TFR(15) TFR(26) TFR(6)
  x0 += ks1; x1 += ks2 + 1u;
  TFR(17) TFR(29) TFR(16) TFR(24)
  x0 += ks2; x1 += ks0 + 2u;
  TFR(13) TFR(15) TFR(26) TFR(6)
  x0 += ks0; x1 += ks1 + 3u;
  TFR(17) TFR(29) TFR(16) TFR(24)
  x0 += ks1; x1 += ks2 + 4u;
  TFR(13) TFR(15) TFR(26) TFR(6)
  x0 += ks2; x1 += ks0 + 5u;
#undef TFR
  o0 = x0; o1 = x1;
}

// Noise bits for flat element i of [B,T,NB,E].
// VARIANT 2: partitionable, XOR fold (bits1 ^ bits2) of threefry(key,(0,i)) —
//   jax/_src/prng.py narrows 64-bit partitionable bits to 8/16/32 via bits1^bits2.
// (ladder: 0 = hi word [FAILED R4/R5], 1 = lo word [FAILED R6], 3 = legacy iota-split)
#define NOISE_VARIANT 2
__device__ __forceinline__ u32 noise_bits(u32 b, u32 i0) {   // i0 = flat within b
#if NOISE_VARIANT == 3
  u32 o0, o1; tf_0_42(i0, i0 + HALF_, o0, o1);
  return b ? o1 : o0;
#else
  u32 i = b * HALF_ + i0;
  u32 o0, o1; tf_0_42(0u, i, o0, o1);
#if NOISE_VARIANT == 0
  return o0;
#elif NOISE_VARIANT == 1
  return o1;
#else
  return o0 ^ o1;
#endif
#endif
}

// noise = 1 - uniform = 2 - bitcast(bits>>9 | 0x3F800000)   (exact in fp32)
__device__ __forceinline__ float noise_of(u32 bits) {
  float f = __uint_as_float((bits >> 9) | 0x3F800000u);
  return 2.0f - f;
}

// order-preserving map fp32 -> u32 (finite)
__device__ __forceinline__ u32 map_f32(float v) {
  u32 u = __float_as_uint(v);
  return ((int)u >= 0) ? (u | 0x80000000u) : ~u;
}

// ---------------- Kernel 1: logits GEMM (fp32 stage, f64 accumulate) ----------------
#define BM 64
#define BN 64
#define BK 16

__global__ __launch_bounds__(256) void gemm_logits(const float* __restrict__ x,
                                                   const float* __restrict__ W,
                                                   float* __restrict__ logits) {
  __shared__ float As[BK][BM + 2];
  __shared__ float Bs[BK][BN + 2];

  const int n  = blockIdx.z;
  const int m0 = blockIdx.y * BM;            // m = b*T + t
  const int e0 = blockIdx.x * BN;
  const int tid = threadIdx.x;
  const int tx = tid & 15;
  const int ty = tid >> 4;

  const float* Abase = x + ((size_t)m0 * NB_ + n) * D_;
  const float* Bbase = W + ((size_t)n * E_ + e0) * D_;

  double acc[4][4];
#pragma unroll
  for (int i = 0; i < 4; ++i)
#pragma unroll
    for (int j = 0; j < 4; ++j) acc[i][j] = 0.0;

  for (int k0 = 0; k0 < D_; k0 += BK) {
#pragma unroll
    for (int l = 0; l < 4; ++l) {
      int flat = tid + l * 256;
      int r = flat >> 4;                     // 0..63
      int c = flat & 15;                     // 0..15
      As[c][r] = Abase[(size_t)r * (NB_ * D_) + (k0 + c)];
      Bs[c][r] = Bbase[(size_t)r * D_ + (k0 + c)];
    }
    __syncthreads();
#pragma unroll
    for (int kk = 0; kk < BK; ++kk) {
      double a[4], b[4];
#pragma unroll
      for (int i = 0; i < 4; ++i) a[i] = (double)As[kk][i * 16 + ty];
#pragma unroll
      for (int j = 0; j < 4; ++j) b[j] = (double)Bs[kk][j * 16 + tx];
#pragma unroll
      for (int i = 0; i < 4; ++i)
#pragma unroll
        for (int j = 0; j < 4; ++j) acc[i][j] = fma(a[i], b[j], acc[i][j]);
    }
    __syncthreads();
  }

#pragma unroll
  for (int i = 0; i < 4; ++i) {
    int m = m0 + i * 16 + ty;
#pragma unroll
    for (int j = 0; j < 4; ++j) {
      int e = e0 + j * 16 + tx;
      logits[((size_t)m * NB_ + n) * E_ + e] = (float)acc[i][j];
    }
  }
}

// ---------------- Kernel 2: per-(b,n,e) top-3 over T -> records (NO atomics) ----------------
__global__ __launch_bounds__(256) void select_store(const float* __restrict__ logits,
                                                    u64* __restrict__ tpak,
                                                    float4* __restrict__ vrec) {
  int gid = blockIdx.x * 256 + threadIdx.x;  // 32768 = B*NB*E;  gid = (b*NB+n)*E + e
  int b  = gid >> 14;
  int ne = gid & (NE_ - 1);

  float v0 = -1e30f, v1 = -1e30f, v2 = -1e30f;
  int   t0 = 0, t1 = 0, t2 = 0;

  const float* lg = logits + (size_t)b * HALF_;
  for (int t = 0; t < T_; ++t) {
    u32 i0 = (u32)t * (u32)NE_ + (u32)ne;
    float y = lg[i0] * noise_of(noise_bits((u32)b, i0));
    if (y > v0)      { v2=v1; t2=t1; v1=v0; t1=t0; v0=y; t0=t; }
    else if (y > v1) { v2=v1; t2=t1; v1=y;  t1=t; }
    else if (y > v2) { v2=y;  t2=t; }
  }

  tpak[gid] = (u64)(u32)t0 | ((u64)(u32)t1 << 16) | ((u64)(u32)t2 << 32);
  vrec[gid] = make_float4(v0, v1, v2, 0.0f);
}

// ---------------- Kernel 3: per-slot argmax over e (exact ref semantics) ----------------
__global__ __launch_bounds__(256) void argmax_idx(const u64* __restrict__ tpak,
                                                  const float4* __restrict__ vrec,
                                                  float* __restrict__ out_idx) {
  int slot = blockIdx.x * 256 + threadIdx.x;  // (b*T+t)*NB + n
  int n  = slot & (NB_ - 1);
  int bt = slot >> 2;
  int b  = bt >> 12;                           // T = 4096
  int t  = bt & (T_ - 1);

  const u64*    tp = tpak + ((size_t)b * NB_ + n) * E_;
  const float4* vp = vrec + ((size_t)b * NB_ + n) * E_;

  u32 bestHi = 0; int bestE = 0; int haveBest = 0;
  int firstZero = -1;

  for (int e = 0; e < E_; ++e) {
    u64 p = tp[e];
    int m0 = ((u32)(p       & 0xFFFFu) == (u32)t);
    int m1 = ((u32)((p>>16) & 0xFFFFu) == (u32)t);
    int m2 = ((u32)((p>>32) & 0xFFFFu) == (u32)t);
    if (m0 | m1 | m2) {
      float4 v = vp[e];
      float val = m0 ? v.x : (m1 ? v.y : v.z);
      if (val == 0.0f) {                      // masked value exactly +/-0 -> zero class
        if (firstZero < 0) firstZero = e;
      }
      u32 mv = map_f32(val == 0.0f ? 0.0f : val);
      if (!haveBest || mv > bestHi) { bestHi = mv; bestE = e; haveBest = 1; }
    } else {
      if (firstZero < 0) firstZero = e;       // unselected -> masked value 0
    }
  }

  int ans;
  if (haveBest && bestHi > 0x80000000u) ans = bestE;            // positive winner
  else if (firstZero >= 0)              ans = firstZero;        // max is 0 -> first zero
  else                                  ans = bestE;            // degenerate: all-negative
  out_idx[slot] = (float)ans;
}

// ---------------- Kernel 4: latent gather (overwrites record scratch) ----------------
__global__ __launch_bounds__(128) void gather_lat(const float* __restrict__ W,
                                                  const float* __restrict__ out_idx,
                                                  float* __restrict__ out_lat) {
  int slot = blockIdx.x;
  int n = slot & (NB_ - 1);
  int e = ((int)out_idx[slot]) & (E_ - 1);    // clamp defensively (avoid OOB fault)
  const float4 v = ((const float4*)(W + ((size_t)n * E_ + e) * D_))[threadIdx.x];
  ((float4*)(out_lat + (size_t)slot * D_))[threadIdx.x] = v;  // 128 x 16B = 2KB
}

// ---------------- Kernel 5: diagnostics (only fires if indices are ALL zero) ----------------
__global__ __launch_bounds__(256) void diag(const float* __restrict__ logits,
                                            const float* __restrict__ W,
                                            float* __restrict__ out_idx) {
  __shared__ int cnt[256];
  int c = 0;
  for (int i = threadIdx.x; i < SLOTS_; i += 256) c += (out_idx[i] != 0.0f);
  cnt[threadIdx.x] = c;
  __syncthreads();
  for (int s = 128; s > 0; s >>= 1) {
    if (threadIdx.x < s) cnt[threadIdx.x] += cnt[threadIdx.x + s];
    __syncthreads();
  }
  if (threadIdx.x == 0 && cnt[0] == 0) {
    float l = logits[1234567];
    int q1 = (l == 0.0f) ? 1 : (isnan(l) ? 2 : ((fabsf(l) < 1e-3f) ? 3 : 4));
    float v0 = -1e30f;
    for (int t = 0; t < T_; ++t) {
      u32 i0 = (u32)t * (u32)NE_;
      float y = logits[i0] * noise_of(noise_bits(0u, i0));
      if (y > v0) v0 = y;
    }
    int q2 = isnan(v0) ? 3 : (v0 > 0.0f ? 1 : 2);
    int q3 = (W[0] != 0.0f) ? 1 : 0;
    out_idx[0] = 1e4f * (float)(q1 * 100 + q2 * 10 + q3);
  }
}

// ---------------- Launch ----------------
extern "C" void kernel_launch(void* const* d_in, const int* in_sizes, int n_in,
                              void* d_out, int out_size, void* d_ws, size_t ws_size,
                              hipStream_t stream) {
  const float* x = (const float*)d_in[0];    // [B,T,NB*D] fp32
  const float* W = (const float*)d_in[1];    // [NB,E,D]  fp32

  // d_out (float32): indices | latents | logits, flat in return order
  float* out_idx    = (float*)d_out;                          // 32,768
  float* out_lat    = out_idx + (size_t)SLOTS_;               // 16,777,216
  float* out_logits = out_lat + (size_t)SLOTS_ * D_;          // 134,217,728

  // Record scratch lives in the out_lat region (overwritten by gather_lat later).
  u64*    tpak = (u64*)out_lat;
  float4* vrec = (float4*)((char*)out_lat + (size_t)SLOTS_ * sizeof(u64));

  dim3 ggrid(E_ / BN, (B_ * T_) / BM, NB_);
  gemm_logits<<<ggrid, 256, 0, stream>>>(x, W, out_logits);

  select_store<<<SLOTS_ / 256, 256, 0, stream>>>(out_logits, tpak, vrec);

  argmax_idx<<<SLOTS_ / 256, 256, 0, stream>>>(tpak, vrec, out_idx);

  gather_lat<<<SLOTS_, 128, 0, stream>>>(W, out_idx, out_lat);

  diag<<<1, 256, 0, stream>>>(out_logits, W, out_idx);
}

// Round 8
// 4683.740 us; speedup vs baseline: 1.3929x; 1.3929x over previous
//
#include <hip/hip_runtime.h>
#include <stdint.h>

// Problem constants
#define B_     2
#define T_     4096
#define NB_    4
#define D_     512
#define E_     4096
#define NE_    16384           // NB*E
#define HALF_  67108864u       // T*NB*E  (per-b flat block of [B,T,NB,E])
#define SLOTS_ 32768           // B*T*NB

typedef unsigned long long u64;
typedef uint32_t u32;

// ---------------- Threefry-2x32-20, key = (0, 42) ----------------
__device__ __forceinline__ u32 rotl32(u32 x, int r) { return (x << r) | (x >> (32 - r)); }

__device__ __forceinline__ void tf_0_42(u32 x0, u32 x1, u32 &o0, u32 &o1) {
  const u32 ks0 = 0u, ks1 = 42u, ks2 = 0x1BD11BDAu ^ 0u ^ 42u;
  x0 += ks0; x1 += ks1;
#define TFR(r) { x0 += x1; x1 = rotl32(x1, (r)); x1 ^= x0; }
  TFR(13) TFR(15) TFR(26) TFR(6)
  x0 += ks1; x1 += ks2 + 1u;
  TFR(17) TFR(29) TFR(16) TFR(24)
  x0 += ks2; x1 += ks0 + 2u;
  TFR(13) TFR(15) TFR(26) TFR(6)
  x0 += ks0; x1 += ks1 + 3u;
  TFR(17) TFR(29) TFR(16) TFR(24)
  x0 += ks1; x1 += ks2 + 4u;
  TFR(13) TFR(15) TFR(26) TFR(6)
  x0 += ks2; x1 += ks0 + 5u;
#undef TFR
  o0 = x0; o1 = x1;
}

// Partitionable noise bits (VERIFIED R7): XOR fold o0^o1 of threefry(key,(0,i))
__device__ __forceinline__ u32 noise_bits(u32 i) {
  u32 o0, o1; tf_0_42(0u, i, o0, o1);
  return o0 ^ o1;
}

// noise = 1 - uniform = 2 - bitcast(bits>>9 | 0x3F800000)   (exact in fp32)
__device__ __forceinline__ float noise_of(u32 bits) {
  float f = __uint_as_float((bits >> 9) | 0x3F800000u);
  return 2.0f - f;
}

// order-preserving map fp32 -> u32 (finite)
__device__ __forceinline__ u32 map_f32(float v) {
  u32 u = __float_as_uint(v);
  return ((int)u >= 0) ? (u | 0x80000000u) : ~u;
}

#define BASE_KEY 0x80000000FFFFFFFFull   // (+0.0, e=0): empty slot -> argmax 0

// ---------------- Kernel 1: init keys ----------------
__global__ __launch_bounds__(256) void init_keys(u64* __restrict__ keys) {
  int i = blockIdx.x * 256 + threadIdx.x;    // 32768
  keys[i] = BASE_KEY;
}

// ---------------- Kernel 2: logits GEMM (fp32, f32 accumulate) ----------------
#define BM 64
#define BN 64
#define BK 16

__global__ __launch_bounds__(256) void gemm_logits(const float* __restrict__ x,
                                                   const float* __restrict__ W,
                                                   float* __restrict__ logits) {
  __shared__ float As[BK][BM + 2];
  __shared__ float Bs[BK][BN + 2];

  const int n  = blockIdx.z;
  const int m0 = blockIdx.y * BM;            // m = b*T + t
  const int e0 = blockIdx.x * BN;
  const int tid = threadIdx.x;
  const int tx = tid & 15;
  const int ty = tid >> 4;

  const float* Abase = x + ((size_t)m0 * NB_ + n) * D_;
  const float* Bbase = W + ((size_t)n * E_ + e0) * D_;

  float acc[4][4];
#pragma unroll
  for (int i = 0; i < 4; ++i)
#pragma unroll
    for (int j = 0; j < 4; ++j) acc[i][j] = 0.0f;

  for (int k0 = 0; k0 < D_; k0 += BK) {
#pragma unroll
    for (int l = 0; l < 4; ++l) {
      int flat = tid + l * 256;
      int r = flat >> 4;                     // 0..63
      int c = flat & 15;                     // 0..15
      As[c][r] = Abase[(size_t)r * (NB_ * D_) + (k0 + c)];
      Bs[c][r] = Bbase[(size_t)r * D_ + (k0 + c)];
    }
    __syncthreads();
#pragma unroll
    for (int kk = 0; kk < BK; ++kk) {
      float a[4], b[4];
#pragma unroll
      for (int i = 0; i < 4; ++i) a[i] = As[kk][i * 16 + ty];
#pragma unroll
      for (int j = 0; j < 4; ++j) b[j] = Bs[kk][j * 16 + tx];
#pragma unroll
      for (int i = 0; i < 4; ++i)
#pragma unroll
        for (int j = 0; j < 4; ++j) acc[i][j] = fmaf(a[i], b[j], acc[i][j]);
    }
    __syncthreads();
  }

#pragma unroll
  for (int i = 0; i < 4; ++i) {
    int m = m0 + i * 16 + ty;
#pragma unroll
    for (int j = 0; j < 4; ++j) {
      int e = e0 + j * 16 + tx;
      logits[((size_t)m * NB_ + n) * E_ + e] = acc[i][j];
    }
  }
}

// ---------------- Kernel 3: top-3 over t per (b,n,e); scatter argmax candidates ----------------
__global__ __launch_bounds__(256) void select_scatter(const float* __restrict__ logits,
                                                      u64* __restrict__ keys) {
  int gid = blockIdx.x * 256 + threadIdx.x;  // 32768 = B*NB*E
  int b  = gid >> 14;
  int ne = gid & (NE_ - 1);                  // n*E + e

  float v0 = -1e30f, v1 = -1e30f, v2 = -1e30f;
  int   t0 = 0, t1 = 0, t2 = 0;

  const float* lg = logits + (size_t)b * HALF_;
  const u32 ib = (u32)b * HALF_ + (u32)ne;
  for (int t = 0; t < T_; ++t) {
    u32 i0 = (u32)t * (u32)NE_ + (u32)ne;
    float y = lg[i0] * noise_of(noise_bits(ib + (u32)t * (u32)NE_));
    // strict > keeps earlier t on ties (jax top_k tie semantics)
    if (y > v0)      { v2=v1; t2=t1; v1=v0; t1=t0; v0=y; t0=t; }
    else if (y > v1) { v2=v1; t2=t1; v1=y;  t1=t; }
    else if (y > v2) { v2=y;  t2=t; }
  }

  int n = ne >> 12;                          // E = 4096
  int e = ne & (E_ - 1);
  u64 klo = 0xFFFFFFFFull - (u32)e;          // max value wins; tie -> min e
  atomicMax(&keys[((size_t)b * T_ + t0) * NB_ + n], ((u64)map_f32(v0) << 32) | klo);
  atomicMax(&keys[((size_t)b * T_ + t1) * NB_ + n], ((u64)map_f32(v1) << 32) | klo);
  atomicMax(&keys[((size_t)b * T_ + t2) * NB_ + n], ((u64)map_f32(v2) << 32) | klo);
}

// ---------------- Kernel 4: decode argmax -> idx + latent gather ----------------
__global__ __launch_bounds__(128) void finalize(const u64* __restrict__ keys,
                                                const float* __restrict__ W,
                                                float* __restrict__ out_idx,
                                                float* __restrict__ out_lat) {
  int slot = blockIdx.x;                     // (b*T+t)*NB + n
  int n = slot & (NB_ - 1);
  int e = (int)(0xFFFFFFFFu - (u32)keys[slot]) & (E_ - 1);
  if (threadIdx.x == 0) out_idx[slot] = (float)e;

  const float4 v = ((const float4*)(W + ((size_t)n * E_ + e) * D_))[threadIdx.x];
  ((float4*)(out_lat + (size_t)slot * D_))[threadIdx.x] = v;   // 128 x 16B = 2KB
}

// ---------------- Launch ----------------
extern "C" void kernel_launch(void* const* d_in, const int* in_sizes, int n_in,
                              void* d_out, int out_size, void* d_ws, size_t ws_size,
                              hipStream_t stream) {
  const float* x = (const float*)d_in[0];    // [B,T,NB*D] fp32
  const float* W = (const float*)d_in[1];    // [NB,E,D]  fp32

  // d_out (float32): indices | latents | logits, flat in return order
  float* out_idx    = (float*)d_out;                          // 32,768
  float* out_lat    = out_idx + (size_t)SLOTS_;               // 16,777,216
  float* out_logits = out_lat + (size_t)SLOTS_ * D_;          // 134,217,728

  u64* keys = (u64*)d_ws;                                     // 256 KiB

  init_keys<<<SLOTS_ / 256, 256, 0, stream>>>(keys);

  dim3 ggrid(E_ / BN, (B_ * T_) / BM, NB_);
  gemm_logits<<<ggrid, 256, 0, stream>>>(x, W, out_logits);

  select_scatter<<<SLOTS_ / 256, 256, 0, stream>>>(out_logits, keys);

  finalize<<<SLOTS_, 128, 0, stream>>>(keys, W, out_idx, out_lat);
}

// Round 9
// 1940.564 us; speedup vs baseline: 3.3619x; 2.4136x over previous
//
#include <hip/hip_runtime.h>
#include <stdint.h>

// Problem constants
#define B_     2
#define T_     4096
#define NB_    4
#define D_     512
#define E_     4096
#define NE_    16384           // NB*E
#define HALF_  67108864u       // T*NB*E  (per-b flat block of [B,T,NB,E])
#define SLOTS_ 32768           // B*T*NB
#define CHUNKS 8
#define TC_    (T_ / CHUNKS)   // 512

typedef unsigned long long u64;
typedef uint32_t u32;

// ---------------- Threefry-2x32-20, key = (0, 42) ----------------
__device__ __forceinline__ u32 rotl32(u32 x, int r) { return (x << r) | (x >> (32 - r)); }

__device__ __forceinline__ void tf_0_42(u32 x0, u32 x1, u32 &o0, u32 &o1) {
  const u32 ks0 = 0u, ks1 = 42u, ks2 = 0x1BD11BDAu ^ 0u ^ 42u;
  x0 += ks0; x1 += ks1;
#define TFR(r) { x0 += x1; x1 = rotl32(x1, (r)); x1 ^= x0; }
  TFR(13) TFR(15) TFR(26) TFR(6)
  x0 += ks1; x1 += ks2 + 1u;
  TFR(17) TFR(29) TFR(16) TFR(24)
  x0 += ks2; x1 += ks0 + 2u;
  TFR(13) TFR(15) TFR(26) TFR(6)
  x0 += ks0; x1 += ks1 + 3u;
  TFR(17) TFR(29) TFR(16) TFR(24)
  x0 += ks1; x1 += ks2 + 4u;
  TFR(13) TFR(15) TFR(26) TFR(6)
  x0 += ks2; x1 += ks0 + 5u;
#undef TFR
  o0 = x0; o1 = x1;
}

// Partitionable noise bits (VERIFIED R7): XOR fold o0^o1 of threefry(key,(0,i))
__device__ __forceinline__ float noise_at(u32 i) {
  u32 o0, o1; tf_0_42(0u, i, o0, o1);
  u32 bits = o0 ^ o1;
  float f = __uint_as_float((bits >> 9) | 0x3F800000u);  // [1,2)
  return 2.0f - f;                                        // 1 - uniform
}

// order-preserving map fp32 -> u32 (finite)
__device__ __forceinline__ u32 map_f32(float v) {
  u32 u = __float_as_uint(v);
  return ((int)u >= 0) ? (u | 0x80000000u) : ~u;
}

#define BASE_KEY 0x80000000FFFFFFFFull   // (+0.0, e=0): empty slot -> argmax 0

// ---------------- Kernel 1: init keys ----------------
__global__ __launch_bounds__(256) void init_keys(u64* __restrict__ keys) {
  int i = blockIdx.x * 256 + threadIdx.x;    // 32768
  keys[i] = BASE_KEY;
}

// ---------------- Kernel 2: logits GEMM (fp32, 128x128 tile, 8x8 micro) ----------------
#define BM 128
#define BN 128
#define BK 16
#define LDP (BM + 4)   // padded leading dim

__global__ __launch_bounds__(256) void gemm_logits(const float* __restrict__ x,
                                                   const float* __restrict__ W,
                                                   float* __restrict__ logits) {
  __shared__ float As[BK][LDP];
  __shared__ float Bs[BK][LDP];

  const int n  = blockIdx.z;
  const int m0 = blockIdx.y * BM;            // m = b*T + t
  const int e0 = blockIdx.x * BN;
  const int tid = threadIdx.x;
  const int tx = tid & 15;                   // 0..15
  const int ty = tid >> 4;                   // 0..15

  const float* Abase = x + ((size_t)m0 * NB_ + n) * D_;   // row stride NB_*D_
  const float* Bbase = W + ((size_t)n * E_ + e0) * D_;    // row stride D_

  float acc[8][8];
#pragma unroll
  for (int i = 0; i < 8; ++i)
#pragma unroll
    for (int j = 0; j < 8; ++j) acc[i][j] = 0.0f;

  for (int k0 = 0; k0 < D_; k0 += BK) {
    // stage 128x16 of A and B (512 float4s each; 2 per thread per matrix)
#pragma unroll
    for (int l = 0; l < 2; ++l) {
      int f  = tid + l * 256;                // 0..511
      int r  = f >> 2;                       // 0..127
      int c4 = (f & 3) << 2;                 // 0,4,8,12
      float4 av = *(const float4*)(Abase + (size_t)r * (NB_ * D_) + (k0 + c4));
      As[c4 + 0][r] = av.x; As[c4 + 1][r] = av.y;
      As[c4 + 2][r] = av.z; As[c4 + 3][r] = av.w;
      float4 bv = *(const float4*)(Bbase + (size_t)r * D_ + (k0 + c4));
      Bs[c4 + 0][r] = bv.x; Bs[c4 + 1][r] = bv.y;
      Bs[c4 + 2][r] = bv.z; Bs[c4 + 3][r] = bv.w;
    }
    __syncthreads();

#pragma unroll
    for (int kk = 0; kk < BK; ++kk) {
      float a[8], b[8];
      *(float4*)&a[0] = *(const float4*)&As[kk][ty * 4];
      *(float4*)&a[4] = *(const float4*)&As[kk][64 + ty * 4];
      *(float4*)&b[0] = *(const float4*)&Bs[kk][tx * 4];
      *(float4*)&b[4] = *(const float4*)&Bs[kk][64 + tx * 4];
#pragma unroll
      for (int i = 0; i < 8; ++i)
#pragma unroll
        for (int j = 0; j < 8; ++j) acc[i][j] = fmaf(a[i], b[j], acc[i][j]);
    }
    __syncthreads();
  }

  // write: row blocks {ty*4+ii, 64+ty*4+ii}, col blocks {tx*4, 64+tx*4} as float4
#pragma unroll
  for (int ih = 0; ih < 2; ++ih) {
#pragma unroll
    for (int ii = 0; ii < 4; ++ii) {
      int m = m0 + ih * 64 + ty * 4 + ii;
      float* row = logits + ((size_t)m * NB_ + n) * E_ + e0;
#pragma unroll
      for (int jh = 0; jh < 2; ++jh) {
        float4 v = make_float4(acc[ih * 4 + ii][jh * 4 + 0], acc[ih * 4 + ii][jh * 4 + 1],
                               acc[ih * 4 + ii][jh * 4 + 2], acc[ih * 4 + ii][jh * 4 + 3]);
        *(float4*)(row + jh * 64 + tx * 4) = v;
      }
    }
  }
}

// ---------------- Kernel 3a: per-chunk top-3 over t (8 chunks) ----------------
__global__ __launch_bounds__(256) void select_chunk(const float* __restrict__ logits,
                                                    float4* __restrict__ vrec,
                                                    u64* __restrict__ tpak) {
  int gid = blockIdx.x * 256 + threadIdx.x;  // 0 .. 8*32768-1
  int chunk = gid >> 15;                     // 0..7
  int gid2  = gid & (SLOTS_ - 1);            // b*16384 + ne
  int b  = gid2 >> 14;
  int ne = gid2 & (NE_ - 1);

  float v0 = -1e30f, v1 = -1e30f, v2 = -1e30f;
  int   t0 = 0, t1 = 0, t2 = 0;

  const float* lg = logits + (size_t)b * HALF_;
  const u32 ib = (u32)b * HALF_ + (u32)ne;
  int tbeg = chunk * TC_;
  for (int tt = 0; tt < TC_; ++tt) {
    int t = tbeg + tt;
    u32 i0 = (u32)t * (u32)NE_ + (u32)ne;
    float y = lg[i0] * noise_at(ib + (u32)t * (u32)NE_);
    // strict > keeps earlier t on ties
    if (y > v0)      { v2=v1; t2=t1; v1=v0; t1=t0; v0=y; t0=t; }
    else if (y > v1) { v2=v1; t2=t1; v1=y;  t1=t; }
    else if (y > v2) { v2=y;  t2=t; }
  }

  size_t rec = (size_t)chunk * SLOTS_ + gid2;
  vrec[rec] = make_float4(v0, v1, v2, 0.0f);
  tpak[rec] = (u64)(u32)t0 | ((u64)(u32)t1 << 16) | ((u64)(u32)t2 << 32);
}

// ---------------- Kernel 3b: merge chunk top-3 -> global top-3 -> scatter ----------------
__global__ __launch_bounds__(256) void merge_scatter(const float4* __restrict__ vrec,
                                                     const u64* __restrict__ tpak,
                                                     u64* __restrict__ keys) {
  int gid2 = blockIdx.x * 256 + threadIdx.x;  // 32768 = B*NB*E
  int b  = gid2 >> 14;
  int ne = gid2 & (NE_ - 1);

  float v0 = -1e30f, v1 = -1e30f, v2 = -1e30f;
  int   t0 = 0, t1 = 0, t2 = 0;

  for (int c = 0; c < CHUNKS; ++c) {          // chunk ascending == t ascending
    size_t rec = (size_t)c * SLOTS_ + gid2;
    float4 v = vrec[rec];
    u64 p = tpak[rec];
    int tc[3] = { (int)(p & 0xFFFFu), (int)((p >> 16) & 0xFFFFu), (int)((p >> 32) & 0xFFFFu) };
    float vc[3] = { v.x, v.y, v.z };
#pragma unroll
    for (int j = 0; j < 3; ++j) {
      float y = vc[j]; int t = tc[j];
      if (y > v0)      { v2=v1; t2=t1; v1=v0; t1=t0; v0=y; t0=t; }
      else if (y > v1) { v2=v1; t2=t1; v1=y;  t1=t; }
      else if (y > v2) { v2=y;  t2=t; }
    }
  }

  int n = ne >> 12;
  int e = ne & (E_ - 1);
  u64 klo = 0xFFFFFFFFull - (u32)e;           // max value wins; tie -> min e
  atomicMax(&keys[((size_t)b * T_ + t0) * NB_ + n], ((u64)map_f32(v0) << 32) | klo);
  atomicMax(&keys[((size_t)b * T_ + t1) * NB_ + n], ((u64)map_f32(v1) << 32) | klo);
  atomicMax(&keys[((size_t)b * T_ + t2) * NB_ + n], ((u64)map_f32(v2) << 32) | klo);
}

// ---------------- Kernel 3 (fallback, no ws records): monolithic select ----------------
__global__ __launch_bounds__(256) void select_scatter(const float* __restrict__ logits,
                                                      u64* __restrict__ keys) {
  int gid = blockIdx.x * 256 + threadIdx.x;  // 32768 = B*NB*E
  int b  = gid >> 14;
  int ne = gid & (NE_ - 1);

  float v0 = -1e30f, v1 = -1e30f, v2 = -1e30f;
  int   t0 = 0, t1 = 0, t2 = 0;

  const float* lg = logits + (size_t)b * HALF_;
  const u32 ib = (u32)b * HALF_ + (u32)ne;
  for (int t = 0; t < T_; ++t) {
    u32 i0 = (u32)t * (u32)NE_ + (u32)ne;
    float y = lg[i0] * noise_at(ib + (u32)t * (u32)NE_);
    if (y > v0)      { v2=v1; t2=t1; v1=v0; t1=t0; v0=y; t0=t; }
    else if (y > v1) { v2=v1; t2=t1; v1=y;  t1=t; }
    else if (y > v2) { v2=y;  t2=t; }
  }

  int n = ne >> 12;
  int e = ne & (E_ - 1);
  u64 klo = 0xFFFFFFFFull - (u32)e;
  atomicMax(&keys[((size_t)b * T_ + t0) * NB_ + n], ((u64)map_f32(v0) << 32) | klo);
  atomicMax(&keys[((size_t)b * T_ + t1) * NB_ + n], ((u64)map_f32(v1) << 32) | klo);
  atomicMax(&keys[((size_t)b * T_ + t2) * NB_ + n], ((u64)map_f32(v2) << 32) | klo);
}

// ---------------- Kernel 4: decode argmax -> idx + latent gather ----------------
__global__ __launch_bounds__(128) void finalize(const u64* __restrict__ keys,
                                                const float* __restrict__ W,
                                                float* __restrict__ out_idx,
                                                float* __restrict__ out_lat) {
  int slot = blockIdx.x;                     // (b*T+t)*NB + n
  int n = slot & (NB_ - 1);
  int e = (int)(0xFFFFFFFFu - (u32)keys[slot]) & (E_ - 1);
  if (threadIdx.x == 0) out_idx[slot] = (float)e;

  const float4 v = ((const float4*)(W + ((size_t)n * E_ + e) * D_))[threadIdx.x];
  ((float4*)(out_lat + (size_t)slot * D_))[threadIdx.x] = v;   // 128 x 16B = 2KB
}

// ---------------- Launch ----------------
extern "C" void kernel_launch(void* const* d_in, const int* in_sizes, int n_in,
                              void* d_out, int out_size, void* d_ws, size_t ws_size,
                              hipStream_t stream) {
  const float* x = (const float*)d_in[0];    // [B,T,NB*D] fp32
  const float* W = (const float*)d_in[1];    // [NB,E,D]  fp32

  float* out_idx    = (float*)d_out;                          // 32,768
  float* out_lat    = out_idx + (size_t)SLOTS_;               // 16,777,216
  float* out_logits = out_lat + (size_t)SLOTS_ * D_;          // 134,217,728

  u64* keys = (u64*)d_ws;                                     // 256 KiB
  const size_t KEYS_B = (size_t)SLOTS_ * 8;
  const size_t VREC_B = (size_t)CHUNKS * SLOTS_ * 16;         // 4 MiB
  const size_t TPAK_B = (size_t)CHUNKS * SLOTS_ * 8;          // 2 MiB
  bool chunked = ws_size >= KEYS_B + VREC_B + TPAK_B;
  float4* vrec = (float4*)((char*)d_ws + KEYS_B);
  u64*    tpak = (u64*)((char*)d_ws + KEYS_B + VREC_B);

  init_keys<<<SLOTS_ / 256, 256, 0, stream>>>(keys);

  dim3 ggrid(E_ / BN, (B_ * T_) / BM, NB_);
  gemm_logits<<<ggrid, 256, 0, stream>>>(x, W, out_logits);

  if (chunked) {
    select_chunk<<<(CHUNKS * SLOTS_) / 256, 256, 0, stream>>>(out_logits, vrec, tpak);
    merge_scatter<<<SLOTS_ / 256, 256, 0, stream>>>(vrec, tpak, keys);
  } else {
    select_scatter<<<SLOTS_ / 256, 256, 0, stream>>>(out_logits, keys);
  }

  finalize<<<SLOTS_, 128, 0, stream>>>(keys, W, out_idx, out_lat);
}

// Round 10
// 971.029 us; speedup vs baseline: 6.7187x; 1.9985x over previous
//
#include <hip/hip_runtime.h>
#include <stdint.h>

// Problem constants
#define B_     2
#define T_     4096
#define NB_    4
#define D_     512
#define E_     4096
#define NE_    16384           // NB*E
#define HALF_  67108864u       // T*NB*E  (per-b flat block of [B,T,NB,E])
#define SLOTS_ 32768           // B*T*NB
#define CHUNKS 8
#define TC_    (T_ / CHUNKS)   // 512

typedef unsigned long long u64;
typedef uint32_t u32;
typedef _Float16 f16x8 __attribute__((ext_vector_type(8)));
typedef float    f32x4 __attribute__((ext_vector_type(4)));

// ---------------- Threefry-2x32-20, key = (0, 42) ----------------
__device__ __forceinline__ u32 rotl32(u32 x, int r) { return (x << r) | (x >> (32 - r)); }

__device__ __forceinline__ void tf_0_42(u32 x0, u32 x1, u32 &o0, u32 &o1) {
  const u32 ks0 = 0u, ks1 = 42u, ks2 = 0x1BD11BDAu ^ 0u ^ 42u;
  x0 += ks0; x1 += ks1;
#define TFR(r) { x0 += x1; x1 = rotl32(x1, (r)); x1 ^= x0; }
  TFR(13) TFR(15) TFR(26) TFR(6)
  x0 += ks1; x1 += ks2 + 1u;
  TFR(17) TFR(29) TFR(16) TFR(24)
  x0 += ks2; x1 += ks0 + 2u;
  TFR(13) TFR(15) TFR(26) TFR(6)
  x0 += ks0; x1 += ks1 + 3u;
  TFR(17) TFR(29) TFR(16) TFR(24)
  x0 += ks1; x1 += ks2 + 4u;
  TFR(13) TFR(15) TFR(26) TFR(6)
  x0 += ks2; x1 += ks0 + 5u;
#undef TFR
  o0 = x0; o1 = x1;
}

// Partitionable noise (VERIFIED R7): XOR fold o0^o1 of threefry(key,(0,i))
__device__ __forceinline__ float noise_at(u32 i) {
  u32 o0, o1; tf_0_42(0u, i, o0, o1);
  u32 bits = o0 ^ o1;
  float f = __uint_as_float((bits >> 9) | 0x3F800000u);  // [1,2)
  return 2.0f - f;                                        // 1 - uniform
}

// order-preserving map fp32 -> u32 (finite)
__device__ __forceinline__ u32 map_f32(float v) {
  u32 u = __float_as_uint(v);
  return ((int)u >= 0) ? (u | 0x80000000u) : ~u;
}

#define BASE_KEY 0x80000000FFFFFFFFull   // (+0.0, e=0): empty slot -> argmax 0

// ---------------- Kernel 1: init keys ----------------
__global__ __launch_bounds__(256) void init_keys(u64* __restrict__ keys) {
  int i = blockIdx.x * 256 + threadIdx.x;    // 32768
  keys[i] = BASE_KEY;
}

// ---------------- Kernel 2: logits GEMM via split-fp16 MFMA ----------------
// C = x . W^T per codebook n.  Split (scaled by 2^11, exact): v*2048 = vh + vl (fp16).
// 3 MFMAs per fragment pair: hh + hl + lh; ll term ~2^-22 (dropped).
// Epilogue descales by 2^-22 (exact).  Error class == fp32 accumulation (R8-proven).
#define BM 128
#define BN 128
#define BK 32
#define SCALE_   2048.0f
#define INV_SC   (1.0f / 4194304.0f)   // 2^-22

__device__ __forceinline__ void split8(const float* __restrict__ p, f16x8 &hi, f16x8 &lo) {
  float4 a0 = *(const float4*)p;
  float4 a1 = *(const float4*)(p + 4);
  float fv[8] = {a0.x, a0.y, a0.z, a0.w, a1.x, a1.y, a1.z, a1.w};
#pragma unroll
  for (int j = 0; j < 8; ++j) {
    float f = fv[j] * SCALE_;
    _Float16 h = (_Float16)f;
    hi[j] = h;
    lo[j] = (_Float16)(f - (float)h);
  }
}

__global__ __launch_bounds__(256) void gemm_logits(const float* __restrict__ x,
                                                   const float* __restrict__ W,
                                                   float* __restrict__ logits) {
  // LDS: 4 buffers of 128 rows x 32 halfs (row = 4 slots of 8 halfs, XOR-swizzled)
  __shared__ f16x8 AhV[128 * 4];
  __shared__ f16x8 AlV[128 * 4];
  __shared__ f16x8 BhV[128 * 4];
  __shared__ f16x8 BlV[128 * 4];

  const int n  = blockIdx.z;
  const int m0 = blockIdx.y * BM;            // m = b*T + t
  const int e0 = blockIdx.x * BN;
  const int tid  = threadIdx.x;
  const int lane = tid & 63;
  const int wid  = tid >> 6;                 // 4 waves: 2x2
  const int wr   = wid >> 1;                 // m-half
  const int wc   = wid & 1;                  // e-half
  const int lm   = lane & 15;
  const int lk   = lane >> 4;                // k-group 0..3

  const float* Abase = x + ((size_t)m0 * NB_ + n) * D_;   // row stride NB_*D_
  const float* Bbase = W + ((size_t)n * E_ + e0) * D_;    // row stride D_

  f32x4 acc[4][4];
#pragma unroll
  for (int i = 0; i < 4; ++i)
#pragma unroll
    for (int j = 0; j < 4; ++j) acc[i][j] = (f32x4){0.f, 0.f, 0.f, 0.f};

  for (int k0 = 0; k0 < D_; k0 += BK) {
    // ---- stage: fp32 -> (hi,lo) fp16 into swizzled LDS ----
#pragma unroll
    for (int l = 0; l < 2; ++l) {
      int aid = tid + l * 256;               // 0..511
      int r   = aid >> 2;                    // 0..127 (tile row)
      int ko  = aid & 3;                     // k-group
      int ps  = ko ^ ((r >> 1) & 3);         // swizzled slot
      f16x8 hi, lo;
      split8(Abase + (size_t)r * (NB_ * D_) + k0 + ko * 8, hi, lo);
      AhV[r * 4 + ps] = hi; AlV[r * 4 + ps] = lo;
      split8(Bbase + (size_t)r * D_ + k0 + ko * 8, hi, lo);
      BhV[r * 4 + ps] = hi; BlV[r * 4 + ps] = lo;
    }
    __syncthreads();

    // ---- fragments + MFMA ----
    f16x8 bh[4], bl[4];
#pragma unroll
    for (int fn = 0; fn < 4; ++fn) {
      int row = wc * 64 + fn * 16 + lm;
      int ps  = lk ^ ((row >> 1) & 3);
      bh[fn] = BhV[row * 4 + ps];
      bl[fn] = BlV[row * 4 + ps];
    }
#pragma unroll
    for (int fm = 0; fm < 4; ++fm) {
      int row = wr * 64 + fm * 16 + lm;
      int ps  = lk ^ ((row >> 1) & 3);
      f16x8 ah = AhV[row * 4 + ps];
      f16x8 al = AlV[row * 4 + ps];
#pragma unroll
      for (int fn = 0; fn < 4; ++fn) {
        acc[fm][fn] = __builtin_amdgcn_mfma_f32_16x16x32_f16(ah, bh[fn], acc[fm][fn], 0, 0, 0);
        acc[fm][fn] = __builtin_amdgcn_mfma_f32_16x16x32_f16(ah, bl[fn], acc[fm][fn], 0, 0, 0);
        acc[fm][fn] = __builtin_amdgcn_mfma_f32_16x16x32_f16(al, bh[fn], acc[fm][fn], 0, 0, 0);
      }
    }
    __syncthreads();
  }

  // ---- epilogue: descale + store (C/D: col=lane&15, row=(lane>>4)*4+reg) ----
#pragma unroll
  for (int fm = 0; fm < 4; ++fm) {
#pragma unroll
    for (int fn = 0; fn < 4; ++fn) {
#pragma unroll
      for (int r = 0; r < 4; ++r) {
        int m = m0 + wr * 64 + fm * 16 + lk * 4 + r;
        int e = e0 + wc * 64 + fn * 16 + lm;
        logits[((size_t)m * NB_ + n) * E_ + e] = acc[fm][fn][r] * INV_SC;
      }
    }
  }
}

// ---------------- Kernel 3a: per-chunk top-3 over t (8 chunks) ----------------
__global__ __launch_bounds__(256) void select_chunk(const float* __restrict__ logits,
                                                    float4* __restrict__ vrec,
                                                    u64* __restrict__ tpak) {
  int gid = blockIdx.x * 256 + threadIdx.x;  // 0 .. 8*32768-1
  int chunk = gid >> 15;                     // 0..7
  int gid2  = gid & (SLOTS_ - 1);            // b*16384 + ne
  int b  = gid2 >> 14;
  int ne = gid2 & (NE_ - 1);

  float v0 = -1e30f, v1 = -1e30f, v2 = -1e30f;
  int   t0 = 0, t1 = 0, t2 = 0;

  const float* lg = logits + (size_t)b * HALF_;
  const u32 ib = (u32)b * HALF_ + (u32)ne;
  int tbeg = chunk * TC_;
  for (int tt = 0; tt < TC_; ++tt) {
    int t = tbeg + tt;
    u32 i0 = (u32)t * (u32)NE_ + (u32)ne;
    float y = lg[i0] * noise_at(ib + (u32)t * (u32)NE_);
    // strict > keeps earlier t on ties
    if (y > v0)      { v2=v1; t2=t1; v1=v0; t1=t0; v0=y; t0=t; }
    else if (y > v1) { v2=v1; t2=t1; v1=y;  t1=t; }
    else if (y > v2) { v2=y;  t2=t; }
  }

  size_t rec = (size_t)chunk * SLOTS_ + gid2;
  vrec[rec] = make_float4(v0, v1, v2, 0.0f);
  tpak[rec] = (u64)(u32)t0 | ((u64)(u32)t1 << 16) | ((u64)(u32)t2 << 32);
}

// ---------------- Kernel 3b: merge chunk top-3 -> global top-3 -> scatter ----------------
__global__ __launch_bounds__(256) void merge_scatter(const float4* __restrict__ vrec,
                                                     const u64* __restrict__ tpak,
                                                     u64* __restrict__ keys) {
  int gid2 = blockIdx.x * 256 + threadIdx.x;  // 32768 = B*NB*E
  int b  = gid2 >> 14;
  int ne = gid2 & (NE_ - 1);

  float v0 = -1e30f, v1 = -1e30f, v2 = -1e30f;
  int   t0 = 0, t1 = 0, t2 = 0;

  for (int c = 0; c < CHUNKS; ++c) {          // chunk ascending == t ascending
    size_t rec = (size_t)c * SLOTS_ + gid2;
    float4 v = vrec[rec];
    u64 p = tpak[rec];
    int tc[3] = { (int)(p & 0xFFFFu), (int)((p >> 16) & 0xFFFFu), (int)((p >> 32) & 0xFFFFu) };
    float vc[3] = { v.x, v.y, v.z };
#pragma unroll
    for (int j = 0; j < 3; ++j) {
      float y = vc[j]; int t = tc[j];
      if (y > v0)      { v2=v1; t2=t1; v1=v0; t1=t0; v0=y; t0=t; }
      else if (y > v1) { v2=v1; t2=t1; v1=y;  t1=t; }
      else if (y > v2) { v2=y;  t2=t; }
    }
  }

  int n = ne >> 12;
  int e = ne & (E_ - 1);
  u64 klo = 0xFFFFFFFFull - (u32)e;           // max value wins; tie -> min e
  atomicMax(&keys[((size_t)b * T_ + t0) * NB_ + n], ((u64)map_f32(v0) << 32) | klo);
  atomicMax(&keys[((size_t)b * T_ + t1) * NB_ + n], ((u64)map_f32(v1) << 32) | klo);
  atomicMax(&keys[((size_t)b * T_ + t2) * NB_ + n], ((u64)map_f32(v2) << 32) | klo);
}

// ---------------- Kernel 3 (fallback, small ws): monolithic select ----------------
__global__ __launch_bounds__(256) void select_scatter(const float* __restrict__ logits,
                                                      u64* __restrict__ keys) {
  int gid = blockIdx.x * 256 + threadIdx.x;  // 32768 = B*NB*E
  int b  = gid >> 14;
  int ne = gid & (NE_ - 1);

  float v0 = -1e30f, v1 = -1e30f, v2 = -1e30f;
  int   t0 = 0, t1 = 0, t2 = 0;

  const float* lg = logits + (size_t)b * HALF_;
  const u32 ib = (u32)b * HALF_ + (u32)ne;
  for (int t = 0; t < T_; ++t) {
    u32 i0 = (u32)t * (u32)NE_ + (u32)ne;
    float y = lg[i0] * noise_at(ib + (u32)t * (u32)NE_);
    if (y > v0)      { v2=v1; t2=t1; v1=v0; t1=t0; v0=y; t0=t; }
    else if (y > v1) { v2=v1; t2=t1; v1=y;  t1=t; }
    else if (y > v2) { v2=y;  t2=t; }
  }

  int n = ne >> 12;
  int e = ne & (E_ - 1);
  u64 klo = 0xFFFFFFFFull - (u32)e;
  atomicMax(&keys[((size_t)b * T_ + t0) * NB_ + n], ((u64)map_f32(v0) << 32) | klo);
  atomicMax(&keys[((size_t)b * T_ + t1) * NB_ + n], ((u64)map_f32(v1) << 32) | klo);
  atomicMax(&keys[((size_t)b * T_ + t2) * NB_ + n], ((u64)map_f32(v2) << 32) | klo);
}

// ---------------- Kernel 4: decode argmax -> idx + latent gather ----------------
__global__ __launch_bounds__(128) void finalize(const u64* __restrict__ keys,
                                                const float* __restrict__ W,
                                                float* __restrict__ out_idx,
                                                float* __restrict__ out_lat) {
  int slot = blockIdx.x;                     // (b*T+t)*NB + n
  int n = slot & (NB_ - 1);
  int e = (int)(0xFFFFFFFFu - (u32)keys[slot]) & (E_ - 1);
  if (threadIdx.x == 0) out_idx[slot] = (float)e;

  const float4 v = ((const float4*)(W + ((size_t)n * E_ + e) * D_))[threadIdx.x];
  ((float4*)(out_lat + (size_t)slot * D_))[threadIdx.x] = v;   // 128 x 16B = 2KB
}

// ---------------- Launch ----------------
extern "C" void kernel_launch(void* const* d_in, const int* in_sizes, int n_in,
                              void* d_out, int out_size, void* d_ws, size_t ws_size,
                              hipStream_t stream) {
  const float* x = (const float*)d_in[0];    // [B,T,NB*D] fp32
  const float* W = (const float*)d_in[1];    // [NB,E,D]  fp32

  float* out_idx    = (float*)d_out;                          // 32,768
  float* out_lat    = out_idx + (size_t)SLOTS_;               // 16,777,216
  float* out_logits = out_lat + (size_t)SLOTS_ * D_;          // 134,217,728

  u64* keys = (u64*)d_ws;                                     // 256 KiB
  const size_t KEYS_B = (size_t)SLOTS_ * 8;
  const size_t VREC_B = (size_t)CHUNKS * SLOTS_ * 16;         // 4 MiB
  const size_t TPAK_B = (size_t)CHUNKS * SLOTS_ * 8;          // 2 MiB
  bool chunked = ws_size >= KEYS_B + VREC_B + TPAK_B;
  float4* vrec = (float4*)((char*)d_ws + KEYS_B);
  u64*    tpak = (u64*)((char*)d_ws + KEYS_B + VREC_B);

  init_keys<<<SLOTS_ / 256, 256, 0, stream>>>(keys);

  dim3 ggrid(E_ / BN, (B_ * T_) / BM, NB_);
  gemm_logits<<<ggrid, 256, 0, stream>>>(x, W, out_logits);

  if (chunked) {
    select_chunk<<<(CHUNKS * SLOTS_) / 256, 256, 0, stream>>>(out_logits, vrec, tpak);
    merge_scatter<<<SLOTS_ / 256, 256, 0, stream>>>(vrec, tpak, keys);
  } else {
    select_scatter<<<SLOTS_ / 256, 256, 0, stream>>>(out_logits, keys);
  }

  finalize<<<SLOTS_, 128, 0, stream>>>(keys, W, out_idx, out_lat);
}

// Round 11
// 948.704 us; speedup vs baseline: 6.8768x; 1.0235x over previous
//
#include <hip/hip_runtime.h>
#include <stdint.h>

// Problem constants
#define B_     2
#define T_     4096
#define NB_    4
#define D_     512
#define E_     4096
#define NE_    16384           // NB*E
#define HALF_  67108864u       // T*NB*E  (per-b flat block of [B,T,NB,E])
#define SLOTS_ 32768           // B*T*NB
#define CHUNKS 8
#define TC_    (T_ / CHUNKS)   // 512
#define XN8_   2097152         // B*T*NB*D/8
#define WN8_   1048576         // NB*E*D/8

typedef unsigned long long u64;
typedef uint32_t u32;
typedef _Float16 f16x8 __attribute__((ext_vector_type(8)));
typedef float    f32x4 __attribute__((ext_vector_type(4)));

// ---------------- Threefry-2x32-20, key = (0, 42) ----------------
__device__ __forceinline__ u32 rotl32(u32 x, int r) { return (x << r) | (x >> (32 - r)); }

__device__ __forceinline__ void tf_0_42(u32 x0, u32 x1, u32 &o0, u32 &o1) {
  const u32 ks0 = 0u, ks1 = 42u, ks2 = 0x1BD11BDAu ^ 0u ^ 42u;
  x0 += ks0; x1 += ks1;
#define TFR(r) { x0 += x1; x1 = rotl32(x1, (r)); x1 ^= x0; }
  TFR(13) TFR(15) TFR(26) TFR(6)
  x0 += ks1; x1 += ks2 + 1u;
  TFR(17) TFR(29) TFR(16) TFR(24)
  x0 += ks2; x1 += ks0 + 2u;
  TFR(13) TFR(15) TFR(26) TFR(6)
  x0 += ks0; x1 += ks1 + 3u;
  TFR(17) TFR(29) TFR(16) TFR(24)
  x0 += ks1; x1 += ks2 + 4u;
  TFR(13) TFR(15) TFR(26) TFR(6)
  x0 += ks2; x1 += ks0 + 5u;
#undef TFR
  o0 = x0; o1 = x1;
}

// Partitionable noise (VERIFIED R7): XOR fold o0^o1 of threefry(key,(0,i))
__device__ __forceinline__ float noise_at(u32 i) {
  u32 o0, o1; tf_0_42(0u, i, o0, o1);
  u32 bits = o0 ^ o1;
  float f = __uint_as_float((bits >> 9) | 0x3F800000u);  // [1,2)
  return 2.0f - f;                                        // 1 - uniform
}

// order-preserving map fp32 -> u32 (finite)
__device__ __forceinline__ u32 map_f32(float v) {
  u32 u = __float_as_uint(v);
  return ((int)u >= 0) ? (u | 0x80000000u) : ~u;
}

#define BASE_KEY 0x80000000FFFFFFFFull   // (+0.0, e=0): empty slot -> argmax 0
#define SCALE_   2048.0f
#define INV_SC   (1.0f / 4194304.0f)     // 2^-22

// ---------------- Kernel 1: init keys ----------------
__global__ __launch_bounds__(256) void init_keys(u64* __restrict__ keys) {
  int i = blockIdx.x * 256 + threadIdx.x;    // 32768
  keys[i] = BASE_KEY;
}

// ---------------- Kernel 1b: pre-split fp32 -> (hi,lo) fp16, scaled by 2^11 ----------------
__device__ __forceinline__ void split8v(const float4 a0, const float4 a1, f16x8 &hi, f16x8 &lo) {
  float fv[8] = {a0.x, a0.y, a0.z, a0.w, a1.x, a1.y, a1.z, a1.w};
#pragma unroll
  for (int j = 0; j < 8; ++j) {
    float f = fv[j] * SCALE_;
    _Float16 h = (_Float16)f;
    hi[j] = h;
    lo[j] = (_Float16)(f - (float)h);
  }
}

__global__ __launch_bounds__(256) void presplit(const float* __restrict__ x,
                                                const float* __restrict__ W,
                                                f16x8* __restrict__ xh, f16x8* __restrict__ xl,
                                                f16x8* __restrict__ wh, f16x8* __restrict__ wl) {
  size_t g = (size_t)blockIdx.x * 256 + threadIdx.x;   // unit = 8 floats
  const float4* src;
  f16x8 *dh, *dl;
  size_t off;
  if (g < XN8_) { src = (const float4*)x; dh = xh; dl = xl; off = g; }
  else          { src = (const float4*)W; dh = wh; dl = wl; off = g - XN8_; }
  float4 a0 = src[off * 2], a1 = src[off * 2 + 1];
  f16x8 hi, lo;
  split8v(a0, a1, hi, lo);
  dh[off] = hi; dl[off] = lo;
}

// ---------------- Kernel 2: logits GEMM via pre-split fp16 MFMA ----------------
// 3 MFMAs per fragment pair: hh + hl + lh; ll term ~2^-22 (dropped).
// Bit-identical to R10's in-kernel-split version (same split math, same MFMA order).
#define BM 128
#define BN 128
#define BK 32

__global__ __launch_bounds__(256) void gemm_logits_ps(const f16x8* __restrict__ xh,
                                                      const f16x8* __restrict__ xl,
                                                      const f16x8* __restrict__ wh,
                                                      const f16x8* __restrict__ wl,
                                                      float* __restrict__ logits) {
  __shared__ f16x8 AhV[128 * 4];
  __shared__ f16x8 AlV[128 * 4];
  __shared__ f16x8 BhV[128 * 4];
  __shared__ f16x8 BlV[128 * 4];

  const int n  = blockIdx.z;
  const int m0 = blockIdx.y * BM;            // m = b*T + t
  const int e0 = blockIdx.x * BN;
  const int tid  = threadIdx.x;
  const int lane = tid & 63;
  const int wid  = tid >> 6;                 // 4 waves: 2x2
  const int wr   = wid >> 1;
  const int wc   = wid & 1;
  const int lm   = lane & 15;
  const int lk   = lane >> 4;                // k-group 0..3

  f32x4 acc[4][4];
#pragma unroll
  for (int i = 0; i < 4; ++i)
#pragma unroll
    for (int j = 0; j < 4; ++j) acc[i][j] = (f32x4){0.f, 0.f, 0.f, 0.f};

  for (int k0 = 0; k0 < D_ / 8; k0 += 4) {   // K-step = 32 halfs = 4 groups
    // ---- stage: load pre-split f16x8 into swizzled LDS ----
#pragma unroll
    for (int l = 0; l < 2; ++l) {
      int aid = tid + l * 256;               // 0..511
      int r   = aid >> 2;                    // 0..127 (tile row)
      int ko  = aid & 3;                     // k-group
      int ps  = ko ^ ((r >> 1) & 3);         // swizzled slot
      size_t gA = ((size_t)(m0 + r) * NB_ + n) * (D_ / 8) + k0 + ko;
      AhV[r * 4 + ps] = xh[gA];
      AlV[r * 4 + ps] = xl[gA];
      size_t gB = ((size_t)n * E_ + e0 + r) * (D_ / 8) + k0 + ko;
      BhV[r * 4 + ps] = wh[gB];
      BlV[r * 4 + ps] = wl[gB];
    }
    __syncthreads();

    f16x8 bh[4], bl[4];
#pragma unroll
    for (int fn = 0; fn < 4; ++fn) {
      int row = wc * 64 + fn * 16 + lm;
      int ps  = lk ^ ((row >> 1) & 3);
      bh[fn] = BhV[row * 4 + ps];
      bl[fn] = BlV[row * 4 + ps];
    }
#pragma unroll
    for (int fm = 0; fm < 4; ++fm) {
      int row = wr * 64 + fm * 16 + lm;
      int ps  = lk ^ ((row >> 1) & 3);
      f16x8 ah = AhV[row * 4 + ps];
      f16x8 al = AlV[row * 4 + ps];
#pragma unroll
      for (int fn = 0; fn < 4; ++fn) {
        acc[fm][fn] = __builtin_amdgcn_mfma_f32_16x16x32_f16(ah, bh[fn], acc[fm][fn], 0, 0, 0);
        acc[fm][fn] = __builtin_amdgcn_mfma_f32_16x16x32_f16(ah, bl[fn], acc[fm][fn], 0, 0, 0);
        acc[fm][fn] = __builtin_amdgcn_mfma_f32_16x16x32_f16(al, bh[fn], acc[fm][fn], 0, 0, 0);
      }
    }
    __syncthreads();
  }

  // ---- epilogue: descale + store (C/D: col=lane&15, row=(lane>>4)*4+reg) ----
#pragma unroll
  for (int fm = 0; fm < 4; ++fm) {
#pragma unroll
    for (int fn = 0; fn < 4; ++fn) {
#pragma unroll
      for (int r = 0; r < 4; ++r) {
        int m = m0 + wr * 64 + fm * 16 + lk * 4 + r;
        int e = e0 + wc * 64 + fn * 16 + lm;
        logits[((size_t)m * NB_ + n) * E_ + e] = acc[fm][fn][r] * INV_SC;
      }
    }
  }
}

// ---------------- Kernel 2-fallback: in-kernel split (R10, proven) ----------------
__device__ __forceinline__ void split8(const float* __restrict__ p, f16x8 &hi, f16x8 &lo) {
  float4 a0 = *(const float4*)p;
  float4 a1 = *(const float4*)(p + 4);
  split8v(a0, a1, hi, lo);
}

__global__ __launch_bounds__(256) void gemm_logits_fb(const float* __restrict__ x,
                                                      const float* __restrict__ W,
                                                      float* __restrict__ logits) {
  __shared__ f16x8 AhV[128 * 4];
  __shared__ f16x8 AlV[128 * 4];
  __shared__ f16x8 BhV[128 * 4];
  __shared__ f16x8 BlV[128 * 4];

  const int n  = blockIdx.z;
  const int m0 = blockIdx.y * BM;
  const int e0 = blockIdx.x * BN;
  const int tid  = threadIdx.x;
  const int lane = tid & 63;
  const int wid  = tid >> 6;
  const int wr   = wid >> 1;
  const int wc   = wid & 1;
  const int lm   = lane & 15;
  const int lk   = lane >> 4;

  const float* Abase = x + ((size_t)m0 * NB_ + n) * D_;
  const float* Bbase = W + ((size_t)n * E_ + e0) * D_;

  f32x4 acc[4][4];
#pragma unroll
  for (int i = 0; i < 4; ++i)
#pragma unroll
    for (int j = 0; j < 4; ++j) acc[i][j] = (f32x4){0.f, 0.f, 0.f, 0.f};

  for (int k0 = 0; k0 < D_; k0 += BK) {
#pragma unroll
    for (int l = 0; l < 2; ++l) {
      int aid = tid + l * 256;
      int r   = aid >> 2;
      int ko  = aid & 3;
      int ps  = ko ^ ((r >> 1) & 3);
      f16x8 hi, lo;
      split8(Abase + (size_t)r * (NB_ * D_) + k0 + ko * 8, hi, lo);
      AhV[r * 4 + ps] = hi; AlV[r * 4 + ps] = lo;
      split8(Bbase + (size_t)r * D_ + k0 + ko * 8, hi, lo);
      BhV[r * 4 + ps] = hi; BlV[r * 4 + ps] = lo;
    }
    __syncthreads();

    f16x8 bh[4], bl[4];
#pragma unroll
    for (int fn = 0; fn < 4; ++fn) {
      int row = wc * 64 + fn * 16 + lm;
      int ps  = lk ^ ((row >> 1) & 3);
      bh[fn] = BhV[row * 4 + ps];
      bl[fn] = BlV[row * 4 + ps];
    }
#pragma unroll
    for (int fm = 0; fm < 4; ++fm) {
      int row = wr * 64 + fm * 16 + lm;
      int ps  = lk ^ ((row >> 1) & 3);
      f16x8 ah = AhV[row * 4 + ps];
      f16x8 al = AlV[row * 4 + ps];
#pragma unroll
      for (int fn = 0; fn < 4; ++fn) {
        acc[fm][fn] = __builtin_amdgcn_mfma_f32_16x16x32_f16(ah, bh[fn], acc[fm][fn], 0, 0, 0);
        acc[fm][fn] = __builtin_amdgcn_mfma_f32_16x16x32_f16(ah, bl[fn], acc[fm][fn], 0, 0, 0);
        acc[fm][fn] = __builtin_amdgcn_mfma_f32_16x16x32_f16(al, bh[fn], acc[fm][fn], 0, 0, 0);
      }
    }
    __syncthreads();
  }

#pragma unroll
  for (int fm = 0; fm < 4; ++fm) {
#pragma unroll
    for (int fn = 0; fn < 4; ++fn) {
#pragma unroll
      for (int r = 0; r < 4; ++r) {
        int m = m0 + wr * 64 + fm * 16 + lk * 4 + r;
        int e = e0 + wc * 64 + fn * 16 + lm;
        logits[((size_t)m * NB_ + n) * E_ + e] = acc[fm][fn][r] * INV_SC;
      }
    }
  }
}

// ---------------- Kernel 3a: per-chunk top-3 over t (8 chunks) ----------------
__global__ __launch_bounds__(256) void select_chunk(const float* __restrict__ logits,
                                                    float4* __restrict__ vrec,
                                                    u64* __restrict__ tpak) {
  int gid = blockIdx.x * 256 + threadIdx.x;  // 0 .. 8*32768-1
  int chunk = gid >> 15;                     // 0..7
  int gid2  = gid & (SLOTS_ - 1);            // b*16384 + ne
  int b  = gid2 >> 14;
  int ne = gid2 & (NE_ - 1);

  float v0 = -1e30f, v1 = -1e30f, v2 = -1e30f;
  int   t0 = 0, t1 = 0, t2 = 0;

  const float* lg = logits + (size_t)b * HALF_;
  const u32 ib = (u32)b * HALF_ + (u32)ne;
  int tbeg = chunk * TC_;
  for (int tt = 0; tt < TC_; ++tt) {
    int t = tbeg + tt;
    u32 i0 = (u32)t * (u32)NE_ + (u32)ne;
    float y = lg[i0] * noise_at(ib + (u32)t * (u32)NE_);
    // strict > keeps earlier t on ties
    if (y > v0)      { v2=v1; t2=t1; v1=v0; t1=t0; v0=y; t0=t; }
    else if (y > v1) { v2=v1; t2=t1; v1=y;  t1=t; }
    else if (y > v2) { v2=y;  t2=t; }
  }

  size_t rec = (size_t)chunk * SLOTS_ + gid2;
  vrec[rec] = make_float4(v0, v1, v2, 0.0f);
  tpak[rec] = (u64)(u32)t0 | ((u64)(u32)t1 << 16) | ((u64)(u32)t2 << 32);
}

// ---------------- Kernel 3b: merge chunk top-3 -> global top-3 -> scatter ----------------
__global__ __launch_bounds__(256) void merge_scatter(const float4* __restrict__ vrec,
                                                     const u64* __restrict__ tpak,
                                                     u64* __restrict__ keys) {
  int gid2 = blockIdx.x * 256 + threadIdx.x;  // 32768 = B*NB*E
  int b  = gid2 >> 14;
  int ne = gid2 & (NE_ - 1);

  float v0 = -1e30f, v1 = -1e30f, v2 = -1e30f;
  int   t0 = 0, t1 = 0, t2 = 0;

  for (int c = 0; c < CHUNKS; ++c) {          // chunk ascending == t ascending
    size_t rec = (size_t)c * SLOTS_ + gid2;
    float4 v = vrec[rec];
    u64 p = tpak[rec];
    int tc[3] = { (int)(p & 0xFFFFu), (int)((p >> 16) & 0xFFFFu), (int)((p >> 32) & 0xFFFFu) };
    float vc[3] = { v.x, v.y, v.z };
#pragma unroll
    for (int j = 0; j < 3; ++j) {
      float y = vc[j]; int t = tc[j];
      if (y > v0)      { v2=v1; t2=t1; v1=v0; t1=t0; v0=y; t0=t; }
      else if (y > v1) { v2=v1; t2=t1; v1=y;  t1=t; }
      else if (y > v2) { v2=y;  t2=t; }
    }
  }

  int n = ne >> 12;
  int e = ne & (E_ - 1);
  u64 klo = 0xFFFFFFFFull - (u32)e;           // max value wins; tie -> min e
  atomicMax(&keys[((size_t)b * T_ + t0) * NB_ + n], ((u64)map_f32(v0) << 32) | klo);
  atomicMax(&keys[((size_t)b * T_ + t1) * NB_ + n], ((u64)map_f32(v1) << 32) | klo);
  atomicMax(&keys[((size_t)b * T_ + t2) * NB_ + n], ((u64)map_f32(v2) << 32) | klo);
}

// ---------------- Kernel 3 (fallback, small ws): monolithic select ----------------
__global__ __launch_bounds__(256) void select_scatter(const float* __restrict__ logits,
                                                      u64* __restrict__ keys) {
  int gid = blockIdx.x * 256 + threadIdx.x;  // 32768 = B*NB*E
  int b  = gid >> 14;
  int ne = gid & (NE_ - 1);

  float v0 = -1e30f, v1 = -1e30f, v2 = -1e30f;
  int   t0 = 0, t1 = 0, t2 = 0;

  const float* lg = logits + (size_t)b * HALF_;
  const u32 ib = (u32)b * HALF_ + (u32)ne;
  for (int t = 0; t < T_; ++t) {
    u32 i0 = (u32)t * (u32)NE_ + (u32)ne;
    float y = lg[i0] * noise_at(ib + (u32)t * (u32)NE_);
    if (y > v0)      { v2=v1; t2=t1; v1=v0; t1=t0; v0=y; t0=t; }
    else if (y > v1) { v2=v1; t2=t1; v1=y;  t1=t; }
    else if (y > v2) { v2=y;  t2=t; }
  }

  int n = ne >> 12;
  int e = ne & (E_ - 1);
  u64 klo = 0xFFFFFFFFull - (u32)e;
  atomicMax(&keys[((size_t)b * T_ + t0) * NB_ + n], ((u64)map_f32(v0) << 32) | klo);
  atomicMax(&keys[((size_t)b * T_ + t1) * NB_ + n], ((u64)map_f32(v1) << 32) | klo);
  atomicMax(&keys[((size_t)b * T_ + t2) * NB_ + n], ((u64)map_f32(v2) << 32) | klo);
}

// ---------------- Kernel 4: decode argmax -> idx + latent gather ----------------
__global__ __launch_bounds__(128) void finalize(const u64* __restrict__ keys,
                                                const float* __restrict__ W,
                                                float* __restrict__ out_idx,
                                                float* __restrict__ out_lat) {
  int slot = blockIdx.x;                     // (b*T+t)*NB + n
  int n = slot & (NB_ - 1);
  int e = (int)(0xFFFFFFFFu - (u32)keys[slot]) & (E_ - 1);
  if (threadIdx.x == 0) out_idx[slot] = (float)e;

  const float4 v = ((const float4*)(W + ((size_t)n * E_ + e) * D_))[threadIdx.x];
  ((float4*)(out_lat + (size_t)slot * D_))[threadIdx.x] = v;   // 128 x 16B = 2KB
}

// ---------------- Launch ----------------
extern "C" void kernel_launch(void* const* d_in, const int* in_sizes, int n_in,
                              void* d_out, int out_size, void* d_ws, size_t ws_size,
                              hipStream_t stream) {
  const float* x = (const float*)d_in[0];    // [B,T,NB*D] fp32
  const float* W = (const float*)d_in[1];    // [NB,E,D]  fp32

  float* out_idx    = (float*)d_out;                          // 32,768
  float* out_lat    = out_idx + (size_t)SLOTS_;               // 16,777,216
  float* out_logits = out_lat + (size_t)SLOTS_ * D_;          // 134,217,728

  // ws layout: keys | vrec | tpak | xh | xl | wh | wl
  u64* keys = (u64*)d_ws;
  const size_t KEYS_B = (size_t)SLOTS_ * 8;                   // 256 KiB
  const size_t VREC_B = (size_t)CHUNKS * SLOTS_ * 16;         // 4 MiB
  const size_t TPAK_B = (size_t)CHUNKS * SLOTS_ * 8;          // 2 MiB
  const size_t XH_B   = (size_t)XN8_ * 16;                    // 32 MiB
  const size_t WH_B   = (size_t)WN8_ * 16;                    // 16 MiB
  bool chunked = ws_size >= KEYS_B + VREC_B + TPAK_B;
  bool split   = ws_size >= KEYS_B + VREC_B + TPAK_B + 2 * XH_B + 2 * WH_B;

  float4* vrec = (float4*)((char*)d_ws + KEYS_B);
  u64*    tpak = (u64*)((char*)d_ws + KEYS_B + VREC_B);
  char*   sp   = (char*)d_ws + KEYS_B + VREC_B + TPAK_B;
  f16x8*  xh   = (f16x8*)sp;
  f16x8*  xl   = (f16x8*)(sp + XH_B);
  f16x8*  wh   = (f16x8*)(sp + 2 * XH_B);
  f16x8*  wl   = (f16x8*)(sp + 2 * XH_B + WH_B);

  init_keys<<<SLOTS_ / 256, 256, 0, stream>>>(keys);

  dim3 ggrid(E_ / BN, (B_ * T_) / BM, NB_);
  if (split) {
    presplit<<<(XN8_ + WN8_) / 256, 256, 0, stream>>>(x, W, xh, xl, wh, wl);
    gemm_logits_ps<<<ggrid, 256, 0, stream>>>(xh, xl, wh, wl, out_logits);
  } else {
    gemm_logits_fb<<<ggrid, 256, 0, stream>>>(x, W, out_logits);
  }

  if (chunked) {
    select_chunk<<<(CHUNKS * SLOTS_) / 256, 256, 0, stream>>>(out_logits, vrec, tpak);
    merge_scatter<<<SLOTS_ / 256, 256, 0, stream>>>(vrec, tpak, keys);
  } else {
    select_scatter<<<SLOTS_ / 256, 256, 0, stream>>>(out_logits, keys);
  }

  finalize<<<SLOTS_, 128, 0, stream>>>(keys, W, out_idx, out_lat);
}

// Round 12
// 792.947 us; speedup vs baseline: 8.2276x; 1.1964x over previous
//
#include <hip/hip_runtime.h>
#include <stdint.h>

// Problem constants
#define B_     2
#define T_     4096
#define NB_    4
#define D_     512
#define E_     4096
#define NE_    16384           // NB*E
#define HALF_  67108864u       // T*NB*E  (per-b flat block of [B,T,NB,E])
#define SLOTS_ 32768           // B*T*NB
#define XN8_   2097152         // B*T*NB*D/8
#define WN8_   1048576         // NB*E*D/8
#define MT_    32              // m-tiles per b = T/128
#define RECN_  (64 * NE_)      // (MT_*B) * NE records per key array

typedef unsigned long long u64;
typedef uint32_t u32;
typedef _Float16 f16x8 __attribute__((ext_vector_type(8)));
typedef float    f32x4 __attribute__((ext_vector_type(4)));

// ---------------- Threefry-2x32-20, key = (0, 42) ----------------
__device__ __forceinline__ u32 rotl32(u32 x, int r) { return __builtin_rotateleft32(x, r); }

__device__ __forceinline__ void tf_0_42(u32 x0, u32 x1, u32 &o0, u32 &o1) {
  const u32 ks0 = 0u, ks1 = 42u, ks2 = 0x1BD11BDAu ^ 0u ^ 42u;
  x0 += ks0; x1 += ks1;
#define TFR(r) { x0 += x1; x1 = rotl32(x1, (r)); x1 ^= x0; }
  TFR(13) TFR(15) TFR(26) TFR(6)
  x0 += ks1; x1 += ks2 + 1u;
  TFR(17) TFR(29) TFR(16) TFR(24)
  x0 += ks2; x1 += ks0 + 2u;
  TFR(13) TFR(15) TFR(26) TFR(6)
  x0 += ks0; x1 += ks1 + 3u;
  TFR(17) TFR(29) TFR(16) TFR(24)
  x0 += ks1; x1 += ks2 + 4u;
  TFR(13) TFR(15) TFR(26) TFR(6)
  x0 += ks2; x1 += ks0 + 5u;
#undef TFR
  o0 = x0; o1 = x1;
}

// Partitionable noise (VERIFIED R7): XOR fold o0^o1 of threefry(key,(0,i))
__device__ __forceinline__ float noise_at(u32 i) {
  u32 o0, o1; tf_0_42(0u, i, o0, o1);
  u32 bits = o0 ^ o1;
  float f = __uint_as_float((bits >> 9) | 0x3F800000u);  // [1,2)
  return 2.0f - f;                                        // 1 - uniform
}

// order-preserving map fp32 -> u32 (finite)
__device__ __forceinline__ u32 map_f32(float v) {
  u32 u = __float_as_uint(v);
  return ((int)u >= 0) ? (u | 0x80000000u) : ~u;
}

// merge two sorted-desc key triples: (a0>=a1>=a2) <- top3 of {a*, b*}
__device__ __forceinline__ void merge3(u64 &a0, u64 &a1, u64 &a2,
                                       u64 b0, u64 b1, u64 b2) {
  u64 o0, o1, o2;
  if (a0 >= b0) {
    o0 = a0;
    if (a1 >= b0) { o1 = a1; o2 = (a2 >= b0) ? a2 : b0; }
    else          { o1 = b0; o2 = (a1 >= b1) ? a1 : b1; }
  } else {
    o0 = b0;
    if (b1 >= a0) { o1 = b1; o2 = (b2 >= a0) ? b2 : a0; }
    else          { o1 = a0; o2 = (b1 >= a1) ? b1 : a1; }
  }
  a0 = o0; a1 = o1; a2 = o2;
}

#define BASE_KEY 0x80000000FFFFFFFFull   // (+0.0, e=0): empty slot -> argmax 0
#define SCALE_   2048.0f
#define INV_SC   (1.0f / 4194304.0f)     // 2^-22

// ---------------- Kernel 1: init keys ----------------
__global__ __launch_bounds__(256) void init_keys(u64* __restrict__ keys) {
  int i = blockIdx.x * 256 + threadIdx.x;    // 32768
  keys[i] = BASE_KEY;
}

// ---------------- Kernel 1b: pre-split fp32 -> (hi,lo) fp16, scaled by 2^11 ----------------
__device__ __forceinline__ void split8v(const float4 a0, const float4 a1, f16x8 &hi, f16x8 &lo) {
  float fv[8] = {a0.x, a0.y, a0.z, a0.w, a1.x, a1.y, a1.z, a1.w};
#pragma unroll
  for (int j = 0; j < 8; ++j) {
    float f = fv[j] * SCALE_;
    _Float16 h = (_Float16)f;
    hi[j] = h;
    lo[j] = (_Float16)(f - (float)h);
  }
}

__global__ __launch_bounds__(256) void presplit(const float* __restrict__ x,
                                                const float* __restrict__ W,
                                                f16x8* __restrict__ xh, f16x8* __restrict__ xl,
                                                f16x8* __restrict__ wh, f16x8* __restrict__ wl) {
  size_t g = (size_t)blockIdx.x * 256 + threadIdx.x;   // unit = 8 floats
  const float4* src;
  f16x8 *dh, *dl;
  size_t off;
  if (g < XN8_) { src = (const float4*)x; dh = xh; dl = xl; off = g; }
  else          { src = (const float4*)W; dh = wh; dl = wl; off = g - XN8_; }
  float4 a0 = src[off * 2], a1 = src[off * 2 + 1];
  f16x8 hi, lo;
  split8v(a0, a1, hi, lo);
  dh[off] = hi; dl[off] = lo;
}

// ---------------- Kernel 2: fused GEMM (split-fp16 MFMA) + noisy top-3 select ----------------
#define BM 128
#define BN 128

__global__ __launch_bounds__(256) void gemm_fused(const f16x8* __restrict__ xh,
                                                  const f16x8* __restrict__ xl,
                                                  const f16x8* __restrict__ wh,
                                                  const f16x8* __restrict__ wl,
                                                  float* __restrict__ logits,
                                                  u64* __restrict__ k0g,
                                                  u64* __restrict__ k1g,
                                                  u64* __restrict__ k2g) {
  __shared__ f16x8 AhV[128 * 4];
  __shared__ f16x8 AlV[128 * 4];
  __shared__ f16x8 BhV[128 * 4];
  __shared__ f16x8 BlV[128 * 4];

  const int n  = blockIdx.z;
  const int m0 = blockIdx.y * BM;            // m = b*T + t
  const int e0 = blockIdx.x * BN;
  const int tid  = threadIdx.x;
  const int lane = tid & 63;
  const int wid  = tid >> 6;                 // 4 waves: wid = wr*2 + wc
  const int wr   = wid >> 1;
  const int wc   = wid & 1;
  const int lm   = lane & 15;
  const int lk   = lane >> 4;                // k-group 0..3

  f32x4 acc[4][4];
#pragma unroll
  for (int i = 0; i < 4; ++i)
#pragma unroll
    for (int j = 0; j < 4; ++j) acc[i][j] = (f32x4){0.f, 0.f, 0.f, 0.f};

  for (int k0 = 0; k0 < D_ / 8; k0 += 4) {   // K-step = 32 halfs = 4 groups
#pragma unroll
    for (int l = 0; l < 2; ++l) {
      int aid = tid + l * 256;               // 0..511
      int r   = aid >> 2;                    // 0..127 (tile row)
      int ko  = aid & 3;                     // k-group
      int ps  = ko ^ ((r >> 1) & 3);         // swizzled slot
      size_t gA = ((size_t)(m0 + r) * NB_ + n) * (D_ / 8) + k0 + ko;
      AhV[r * 4 + ps] = xh[gA];
      AlV[r * 4 + ps] = xl[gA];
      size_t gB = ((size_t)n * E_ + e0 + r) * (D_ / 8) + k0 + ko;
      BhV[r * 4 + ps] = wh[gB];
      BlV[r * 4 + ps] = wl[gB];
    }
    __syncthreads();

    f16x8 bh[4], bl[4];
#pragma unroll
    for (int fn = 0; fn < 4; ++fn) {
      int row = wc * 64 + fn * 16 + lm;
      int ps  = lk ^ ((row >> 1) & 3);
      bh[fn] = BhV[row * 4 + ps];
      bl[fn] = BlV[row * 4 + ps];
    }
#pragma unroll
    for (int fm = 0; fm < 4; ++fm) {
      int row = wr * 64 + fm * 16 + lm;
      int ps  = lk ^ ((row >> 1) & 3);
      f16x8 ah = AhV[row * 4 + ps];
      f16x8 al = AlV[row * 4 + ps];
#pragma unroll
      for (int fn = 0; fn < 4; ++fn) {
        acc[fm][fn] = __builtin_amdgcn_mfma_f32_16x16x32_f16(ah, bh[fn], acc[fm][fn], 0, 0, 0);
        acc[fm][fn] = __builtin_amdgcn_mfma_f32_16x16x32_f16(ah, bl[fn], acc[fm][fn], 0, 0, 0);
        acc[fm][fn] = __builtin_amdgcn_mfma_f32_16x16x32_f16(al, bh[fn], acc[fm][fn], 0, 0, 0);
      }
    }
    __syncthreads();
  }

  // ---- fused epilogue: store logits + per-column noisy top-3 ----
  const int b     = m0 >> 12;                // m0 / T_
  const int mbase = m0 & (T_ - 1);           // t of tile row 0
  const int mtile = mbase >> 7;
  u64* ldsK = (u64*)AhV;                     // repurposed: [4 waves][64 cols][3] u64 = 6 KB

#pragma unroll
  for (int fn = 0; fn < 4; ++fn) {
    const int e = e0 + wc * 64 + fn * 16 + lm;   // e within [0,E)
    u64 K0 = 0, K1 = 0, K2 = 0;
#pragma unroll
    for (int fm = 0; fm < 4; ++fm) {
#pragma unroll
      for (int r = 0; r < 4; ++r) {
        const int t = mbase + wr * 64 + fm * 16 + lk * 4 + r;
        const int m = m0 + wr * 64 + fm * 16 + lk * 4 + r;
        float lg = acc[fm][fn][r] * INV_SC;
        logits[((size_t)m * NB_ + n) * E_ + e] = lg;
        u32 i = (u32)b * HALF_ + (u32)t * (u32)NE_ + (u32)(n * E_ + e);
        float y = lg * noise_at(i);
        u64 key = ((u64)map_f32(y) << 32) | (u64)(0xFFFFFFFFu - (u32)t);
        if (key > K0)      { K2 = K1; K1 = K0; K0 = key; }
        else if (key > K1) { K2 = K1; K1 = key; }
        else if (key > K2) { K2 = key; }
      }
    }
    // merge across the 4 lk-lanes of this lm-group
    u64 p0 = __shfl_xor(K0, 16), p1 = __shfl_xor(K1, 16), p2 = __shfl_xor(K2, 16);
    merge3(K0, K1, K2, p0, p1, p2);
    p0 = __shfl_xor(K0, 32); p1 = __shfl_xor(K1, 32); p2 = __shfl_xor(K2, 32);
    merge3(K0, K1, K2, p0, p1, p2);
    if (lk == 0) {
      int c = fn * 16 + lm;                  // 0..63
      ldsK[(wid * 64 + c) * 3 + 0] = K0;
      ldsK[(wid * 64 + c) * 3 + 1] = K1;
      ldsK[(wid * 64 + c) * 3 + 2] = K2;
    }
  }
  __syncthreads();
  if (wid < 2) {                             // wr==0 waves merge with their wr==1 partner
    int c = lane;                            // 0..63; col = fn*16+lm = c; e = e0 + wc*64 + c
    u64 A0 = ldsK[(wid * 64 + c) * 3 + 0];
    u64 A1 = ldsK[(wid * 64 + c) * 3 + 1];
    u64 A2 = ldsK[(wid * 64 + c) * 3 + 2];
    u64 C0 = ldsK[((wid + 2) * 64 + c) * 3 + 0];
    u64 C1 = ldsK[((wid + 2) * 64 + c) * 3 + 1];
    u64 C2 = ldsK[((wid + 2) * 64 + c) * 3 + 2];
    merge3(A0, A1, A2, C0, C1, C2);
    int eg = e0 + wid * 64 + c;              // wid<2 -> wc == wid
    size_t R = (size_t)(mtile * 2 + b) * NE_ + (size_t)n * E_ + eg;
    k0g[R] = A0; k1g[R] = A1; k2g[R] = A2;
  }
}

// ---------------- Kernel 3: merge tile records -> global top-3 -> slot scatter ----------------
__global__ __launch_bounds__(256) void merge_scatter2(const u64* __restrict__ k0g,
                                                      const u64* __restrict__ k1g,
                                                      const u64* __restrict__ k2g,
                                                      u64* __restrict__ keys) {
  int gid2 = blockIdx.x * 256 + threadIdx.x;  // 32768 = B*NB*E
  int b  = gid2 >> 14;
  int ne = gid2 & (NE_ - 1);

  u64 K0 = 0, K1 = 0, K2 = 0;
  for (int mt = 0; mt < MT_; ++mt) {
    size_t R = (size_t)(mt * 2 + b) * NE_ + ne;
    merge3(K0, K1, K2, k0g[R], k1g[R], k2g[R]);
  }

  int n = ne >> 12;
  u32 e = (u32)(ne & (E_ - 1));
  u64 elo = (u64)(0xFFFFFFFFu - e);
  u32 t0 = 0xFFFFFFFFu - (u32)K0;
  u32 t1 = 0xFFFFFFFFu - (u32)K1;
  u32 t2 = 0xFFFFFFFFu - (u32)K2;
  atomicMax(&keys[((size_t)b * T_ + t0) * NB_ + n], (K0 & 0xFFFFFFFF00000000ull) | elo);
  atomicMax(&keys[((size_t)b * T_ + t1) * NB_ + n], (K1 & 0xFFFFFFFF00000000ull) | elo);
  atomicMax(&keys[((size_t)b * T_ + t2) * NB_ + n], (K2 & 0xFFFFFFFF00000000ull) | elo);
}

// ---------------- Fallback path (small ws): in-kernel-split GEMM + monolithic select ----------------
__device__ __forceinline__ void split8(const float* __restrict__ p, f16x8 &hi, f16x8 &lo) {
  float4 a0 = *(const float4*)p;
  float4 a1 = *(const float4*)(p + 4);
  split8v(a0, a1, hi, lo);
}

__global__ __launch_bounds__(256) void gemm_logits_fb(const float* __restrict__ x,
                                                      const float* __restrict__ W,
                                                      float* __restrict__ logits) {
  __shared__ f16x8 AhV[128 * 4];
  __shared__ f16x8 AlV[128 * 4];
  __shared__ f16x8 BhV[128 * 4];
  __shared__ f16x8 BlV[128 * 4];

  const int n  = blockIdx.z;
  const int m0 = blockIdx.y * BM;
  const int e0 = blockIdx.x * BN;
  const int tid  = threadIdx.x;
  const int lane = tid & 63;
  const int wid  = tid >> 6;
  const int wr   = wid >> 1;
  const int wc   = wid & 1;
  const int lm   = lane & 15;
  const int lk   = lane >> 4;

  const float* Abase = x + ((size_t)m0 * NB_ + n) * D_;
  const float* Bbase = W + ((size_t)n * E_ + e0) * D_;

  f32x4 acc[4][4];
#pragma unroll
  for (int i = 0; i < 4; ++i)
#pragma unroll
    for (int j = 0; j < 4; ++j) acc[i][j] = (f32x4){0.f, 0.f, 0.f, 0.f};

  for (int k0 = 0; k0 < D_; k0 += 32) {
#pragma unroll
    for (int l = 0; l < 2; ++l) {
      int aid = tid + l * 256;
      int r   = aid >> 2;
      int ko  = aid & 3;
      int ps  = ko ^ ((r >> 1) & 3);
      f16x8 hi, lo;
      split8(Abase + (size_t)r * (NB_ * D_) + k0 + ko * 8, hi, lo);
      AhV[r * 4 + ps] = hi; AlV[r * 4 + ps] = lo;
      split8(Bbase + (size_t)r * D_ + k0 + ko * 8, hi, lo);
      BhV[r * 4 + ps] = hi; BlV[r * 4 + ps] = lo;
    }
    __syncthreads();

    f16x8 bh[4], bl[4];
#pragma unroll
    for (int fn = 0; fn < 4; ++fn) {
      int row = wc * 64 + fn * 16 + lm;
      int ps  = lk ^ ((row >> 1) & 3);
      bh[fn] = BhV[row * 4 + ps];
      bl[fn] = BlV[row * 4 + ps];
    }
#pragma unroll
    for (int fm = 0; fm < 4; ++fm) {
      int row = wr * 64 + fm * 16 + lm;
      int ps  = lk ^ ((row >> 1) & 3);
      f16x8 ah = AhV[row * 4 + ps];
      f16x8 al = AlV[row * 4 + ps];
#pragma unroll
      for (int fn = 0; fn < 4; ++fn) {
        acc[fm][fn] = __builtin_amdgcn_mfma_f32_16x16x32_f16(ah, bh[fn], acc[fm][fn], 0, 0, 0);
        acc[fm][fn] = __builtin_amdgcn_mfma_f32_16x16x32_f16(ah, bl[fn], acc[fm][fn], 0, 0, 0);
        acc[fm][fn] = __builtin_amdgcn_mfma_f32_16x16x32_f16(al, bh[fn], acc[fm][fn], 0, 0, 0);
      }
    }
    __syncthreads();
  }

#pragma unroll
  for (int fm = 0; fm < 4; ++fm) {
#pragma unroll
    for (int fn = 0; fn < 4; ++fn) {
#pragma unroll
      for (int r = 0; r < 4; ++r) {
        int m = m0 + wr * 64 + fm * 16 + lk * 4 + r;
        int e = e0 + wc * 64 + fn * 16 + lm;
        logits[((size_t)m * NB_ + n) * E_ + e] = acc[fm][fn][r] * INV_SC;
      }
    }
  }
}

__global__ __launch_bounds__(256) void select_scatter(const float* __restrict__ logits,
                                                      u64* __restrict__ keys) {
  int gid = blockIdx.x * 256 + threadIdx.x;  // 32768 = B*NB*E
  int b  = gid >> 14;
  int ne = gid & (NE_ - 1);

  float v0 = -1e30f, v1 = -1e30f, v2 = -1e30f;
  int   t0 = 0, t1 = 0, t2 = 0;

  const float* lg = logits + (size_t)b * HALF_;
  const u32 ib = (u32)b * HALF_ + (u32)ne;
  for (int t = 0; t < T_; ++t) {
    u32 i0 = (u32)t * (u32)NE_ + (u32)ne;
    float y = lg[i0] * noise_at(ib + (u32)t * (u32)NE_);
    if (y > v0)      { v2=v1; t2=t1; v1=v0; t1=t0; v0=y; t0=t; }
    else if (y > v1) { v2=v1; t2=t1; v1=y;  t1=t; }
    else if (y > v2) { v2=y;  t2=t; }
  }

  int n = ne >> 12;
  int e = ne & (E_ - 1);
  u64 klo = 0xFFFFFFFFull - (u32)e;
  atomicMax(&keys[((size_t)b * T_ + t0) * NB_ + n], ((u64)map_f32(v0) << 32) | klo);
  atomicMax(&keys[((size_t)b * T_ + t1) * NB_ + n], ((u64)map_f32(v1) << 32) | klo);
  atomicMax(&keys[((size_t)b * T_ + t2) * NB_ + n], ((u64)map_f32(v2) << 32) | klo);
}

// ---------------- Kernel 4: decode argmax -> idx + latent gather ----------------
__global__ __launch_bounds__(128) void finalize(const u64* __restrict__ keys,
                                                const float* __restrict__ W,
                                                float* __restrict__ out_idx,
                                                float* __restrict__ out_lat) {
  int slot = blockIdx.x;                     // (b*T+t)*NB + n
  int n = slot & (NB_ - 1);
  int e = (int)(0xFFFFFFFFu - (u32)keys[slot]) & (E_ - 1);
  if (threadIdx.x == 0) out_idx[slot] = (float)e;

  const float4 v = ((const float4*)(W + ((size_t)n * E_ + e) * D_))[threadIdx.x];
  ((float4*)(out_lat + (size_t)slot * D_))[threadIdx.x] = v;   // 128 x 16B = 2KB
}

// ---------------- Launch ----------------
extern "C" void kernel_launch(void* const* d_in, const int* in_sizes, int n_in,
                              void* d_out, int out_size, void* d_ws, size_t ws_size,
                              hipStream_t stream) {
  const float* x = (const float*)d_in[0];    // [B,T,NB*D] fp32
  const float* W = (const float*)d_in[1];    // [NB,E,D]  fp32

  float* out_idx    = (float*)d_out;                          // 32,768
  float* out_lat    = out_idx + (size_t)SLOTS_;               // 16,777,216
  float* out_logits = out_lat + (size_t)SLOTS_ * D_;          // 134,217,728

  // ws layout: keys | xh | xl | wh | wl
  u64* keys = (u64*)d_ws;
  const size_t KEYS_B = (size_t)SLOTS_ * 8;                   // 256 KiB
  const size_t XH_B   = (size_t)XN8_ * 16;                    // 32 MiB
  const size_t WH_B   = (size_t)WN8_ * 16;                    // 16 MiB
  bool split = ws_size >= KEYS_B + 2 * XH_B + 2 * WH_B;       // ~96.3 MB (R11: ws >= 102 MB)

  char*  sp = (char*)d_ws + KEYS_B;
  f16x8* xh = (f16x8*)sp;
  f16x8* xl = (f16x8*)(sp + XH_B);
  f16x8* wh = (f16x8*)(sp + 2 * XH_B);
  f16x8* wl = (f16x8*)(sp + 2 * XH_B + WH_B);

  // tile-select records live in the out_lat region (overwritten by finalize later)
  u64* k0g = (u64*)out_lat;                                   // 8 MB each
  u64* k1g = k0g + RECN_;
  u64* k2g = k1g + RECN_;

  init_keys<<<SLOTS_ / 256, 256, 0, stream>>>(keys);

  dim3 ggrid(E_ / BN, (B_ * T_) / BM, NB_);
  if (split) {
    presplit<<<(XN8_ + WN8_) / 256, 256, 0, stream>>>(x, W, xh, xl, wh, wl);
    gemm_fused<<<ggrid, 256, 0, stream>>>(xh, xl, wh, wl, out_logits, k0g, k1g, k2g);
    merge_scatter2<<<SLOTS_ / 256, 256, 0, stream>>>(k0g, k1g, k2g, keys);
  } else {
    gemm_logits_fb<<<ggrid, 256, 0, stream>>>(x, W, out_logits);
    select_scatter<<<SLOTS_ / 256, 256, 0, stream>>>(out_logits, keys);
  }

  finalize<<<SLOTS_, 128, 0, stream>>>(keys, W, out_idx, out_lat);
}

// Round 13
// 773.031 us; speedup vs baseline: 8.4395x; 1.0258x over previous
//
#include <hip/hip_runtime.h>
#include <stdint.h>

// Problem constants
#define B_     2
#define T_     4096
#define NB_    4
#define D_     512
#define E_     4096
#define NE_    16384           // NB*E
#define HALF_  67108864u       // T*NB*E  (per-b flat block of [B,T,NB,E])
#define SLOTS_ 32768           // B*T*NB
#define XN8_   2097152         // B*T*NB*D/8
#define WN8_   1048576         // NB*E*D/8
#define MT_    32              // m-tiles per b = T/128
#define RECN_  (64 * NE_)      // (MT_*B) * NE records per key array

typedef unsigned long long u64;
typedef uint32_t u32;
typedef _Float16 f16x8 __attribute__((ext_vector_type(8)));
typedef float    f32x4 __attribute__((ext_vector_type(4)));

// ---------------- Threefry-2x32-20, key = (0, 42) ----------------
__device__ __forceinline__ u32 rotl32(u32 x, int r) { return __builtin_rotateleft32(x, r); }

__device__ __forceinline__ void tf_0_42(u32 x0, u32 x1, u32 &o0, u32 &o1) {
  const u32 ks0 = 0u, ks1 = 42u, ks2 = 0x1BD11BDAu ^ 0u ^ 42u;
  x0 += ks0; x1 += ks1;
#define TFR(r) { x0 += x1; x1 = rotl32(x1, (r)); x1 ^= x0; }
  TFR(13) TFR(15) TFR(26) TFR(6)
  x0 += ks1; x1 += ks2 + 1u;
  TFR(17) TFR(29) TFR(16) TFR(24)
  x0 += ks2; x1 += ks0 + 2u;
  TFR(13) TFR(15) TFR(26) TFR(6)
  x0 += ks0; x1 += ks1 + 3u;
  TFR(17) TFR(29) TFR(16) TFR(24)
  x0 += ks1; x1 += ks2 + 4u;
  TFR(13) TFR(15) TFR(26) TFR(6)
  x0 += ks2; x1 += ks0 + 5u;
#undef TFR
  o0 = x0; o1 = x1;
}

// Partitionable noise (VERIFIED R7): XOR fold o0^o1 of threefry(key,(0,i))
__device__ __forceinline__ float noise_at(u32 i) {
  u32 o0, o1; tf_0_42(0u, i, o0, o1);
  u32 bits = o0 ^ o1;
  float f = __uint_as_float((bits >> 9) | 0x3F800000u);  // [1,2)
  return 2.0f - f;                                        // 1 - uniform
}

// order-preserving map fp32 -> u32, branchless (finite inputs)
__device__ __forceinline__ u32 map_f32(float v) {
  u32 u = __float_as_uint(v);
  u32 s = (u32)((int)u >> 31);               // 0 or 0xFFFFFFFF
  return u ^ (s | 0x80000000u);
}

// merge two sorted-desc key triples: (a0>=a1>=a2) <- top3 of {a*, b*}
__device__ __forceinline__ void merge3(u64 &a0, u64 &a1, u64 &a2,
                                       u64 b0, u64 b1, u64 b2) {
  u64 o0, o1, o2;
  if (a0 >= b0) {
    o0 = a0;
    if (a1 >= b0) { o1 = a1; o2 = (a2 >= b0) ? a2 : b0; }
    else          { o1 = b0; o2 = (a1 >= b1) ? a1 : b1; }
  } else {
    o0 = b0;
    if (b1 >= a0) { o1 = b1; o2 = (b2 >= a0) ? b2 : a0; }
    else          { o1 = a0; o2 = (b1 >= a1) ? b1 : a1; }
  }
  a0 = o0; a1 = o1; a2 = o2;
}

#define BASE_KEY 0x80000000FFFFFFFFull   // (+0.0, e=0): empty slot -> argmax 0
#define SCALE_   2048.0f
#define INV_SC   (1.0f / 4194304.0f)     // 2^-22

// ---------------- Kernel 1: init keys ----------------
__global__ __launch_bounds__(256) void init_keys(u64* __restrict__ keys) {
  int i = blockIdx.x * 256 + threadIdx.x;    // 32768
  keys[i] = BASE_KEY;
}

// ---------------- Kernel 1b: pre-split fp32 -> (hi,lo) fp16, scaled by 2^11 ----------------
__device__ __forceinline__ void split8v(const float4 a0, const float4 a1, f16x8 &hi, f16x8 &lo) {
  float fv[8] = {a0.x, a0.y, a0.z, a0.w, a1.x, a1.y, a1.z, a1.w};
#pragma unroll
  for (int j = 0; j < 8; ++j) {
    float f = fv[j] * SCALE_;
    _Float16 h = (_Float16)f;
    hi[j] = h;
    lo[j] = (_Float16)(f - (float)h);
  }
}

__global__ __launch_bounds__(256) void presplit(const float* __restrict__ x,
                                                const float* __restrict__ W,
                                                f16x8* __restrict__ xh, f16x8* __restrict__ xl,
                                                f16x8* __restrict__ wh, f16x8* __restrict__ wl) {
  size_t g = (size_t)blockIdx.x * 256 + threadIdx.x;   // unit = 8 floats
  const float4* src;
  f16x8 *dh, *dl;
  size_t off;
  if (g < XN8_) { src = (const float4*)x; dh = xh; dl = xl; off = g; }
  else          { src = (const float4*)W; dh = wh; dl = wl; off = g - XN8_; }
  float4 a0 = src[off * 2], a1 = src[off * 2 + 1];
  f16x8 hi, lo;
  split8v(a0, a1, hi, lo);
  dh[off] = hi; dl[off] = lo;
}

// ---------------- Kernel 2: fused GEMM (split-fp16 MFMA) + noisy top-3 select ----------------
#define BM 128
#define BN 128

__global__ __launch_bounds__(256) void gemm_fused(const f16x8* __restrict__ xh,
                                                  const f16x8* __restrict__ xl,
                                                  const f16x8* __restrict__ wh,
                                                  const f16x8* __restrict__ wl,
                                                  float* __restrict__ logits,
                                                  u64* __restrict__ k0g,
                                                  u64* __restrict__ k1g,
                                                  u64* __restrict__ k2g) {
  __shared__ f16x8 AhV[128 * 4];
  __shared__ f16x8 AlV[128 * 4];
  __shared__ f16x8 BhV[128 * 4];
  __shared__ f16x8 BlV[128 * 4];

  const int n  = blockIdx.z;
  const int m0 = blockIdx.y * BM;            // m = b*T + t
  const int e0 = blockIdx.x * BN;
  const int tid  = threadIdx.x;
  const int lane = tid & 63;
  const int wid  = tid >> 6;                 // 4 waves: wid = wr*2 + wc
  const int wr   = wid >> 1;
  const int wc   = wid & 1;
  const int lm   = lane & 15;
  const int lk   = lane >> 4;                // k-group 0..3

  f32x4 acc[4][4];
#pragma unroll
  for (int i = 0; i < 4; ++i)
#pragma unroll
    for (int j = 0; j < 4; ++j) acc[i][j] = (f32x4){0.f, 0.f, 0.f, 0.f};

  for (int k0 = 0; k0 < D_ / 8; k0 += 4) {   // K-step = 32 halfs = 4 groups
#pragma unroll
    for (int l = 0; l < 2; ++l) {
      int aid = tid + l * 256;               // 0..511
      int r   = aid >> 2;                    // 0..127 (tile row)
      int ko  = aid & 3;                     // k-group
      int ps  = ko ^ ((r >> 1) & 3);         // swizzled slot
      size_t gA = ((size_t)(m0 + r) * NB_ + n) * (D_ / 8) + k0 + ko;
      AhV[r * 4 + ps] = xh[gA];
      AlV[r * 4 + ps] = xl[gA];
      size_t gB = ((size_t)n * E_ + e0 + r) * (D_ / 8) + k0 + ko;
      BhV[r * 4 + ps] = wh[gB];
      BlV[r * 4 + ps] = wl[gB];
    }
    __syncthreads();

    f16x8 bh[4], bl[4];
#pragma unroll
    for (int fn = 0; fn < 4; ++fn) {
      int row = wc * 64 + fn * 16 + lm;
      int ps  = lk ^ ((row >> 1) & 3);
      bh[fn] = BhV[row * 4 + ps];
      bl[fn] = BlV[row * 4 + ps];
    }
#pragma unroll
    for (int fm = 0; fm < 4; ++fm) {
      int row = wr * 64 + fm * 16 + lm;
      int ps  = lk ^ ((row >> 1) & 3);
      f16x8 ah = AhV[row * 4 + ps];
      f16x8 al = AlV[row * 4 + ps];
#pragma unroll
      for (int fn = 0; fn < 4; ++fn) {
        acc[fm][fn] = __builtin_amdgcn_mfma_f32_16x16x32_f16(ah, bh[fn], acc[fm][fn], 0, 0, 0);
        acc[fm][fn] = __builtin_amdgcn_mfma_f32_16x16x32_f16(ah, bl[fn], acc[fm][fn], 0, 0, 0);
        acc[fm][fn] = __builtin_amdgcn_mfma_f32_16x16x32_f16(al, bh[fn], acc[fm][fn], 0, 0, 0);
      }
    }
    __syncthreads();
  }

  // ---- epilogue part 1: store logits ----
  const int b     = m0 >> 12;                // m0 / T_
  const int mbase = m0 & (T_ - 1);           // t of tile row 0
  const int mtile = mbase >> 7;

#pragma unroll
  for (int fm = 0; fm < 4; ++fm) {
#pragma unroll
    for (int r = 0; r < 4; ++r) {
      int m = m0 + wr * 64 + fm * 16 + lk * 4 + r;
      float* row = logits + ((size_t)m * NB_ + n) * E_ + e0 + wc * 64 + lm;
#pragma unroll
      for (int fn = 0; fn < 4; ++fn) row[fn * 16] = acc[fm][fn][r] * INV_SC;
    }
  }

  // ---- epilogue part 2: per-column noisy top-3 (branchless, 32-bit) ----
  u64* ldsK = (u64*)AhV;                     // repurposed: [4 waves][64 cols][3] u64 = 6 KB

#pragma unroll
  for (int fn = 0; fn < 4; ++fn) {
    const int e = e0 + wc * 64 + fn * 16 + lm;   // e within [0,E)
    u32 v0 = 0, v1 = 0, v2 = 0;                  // mapped values (finite y -> mv > 0)
    u32 tt0 = 0, tt1 = 0, tt2 = 0;
    const u32 ibase = (u32)b * HALF_ + (u32)(n * E_ + e);
#pragma unroll
    for (int fm = 0; fm < 4; ++fm) {             // t ascends within thread
#pragma unroll
      for (int r = 0; r < 4; ++r) {
        const u32 t = (u32)(mbase + wr * 64 + fm * 16 + lk * 4 + r);
        float y = (acc[fm][fn][r] * INV_SC) * noise_at(ibase + t * (u32)NE_);
        u32 mv = map_f32(y);
        bool g0 = mv > v0, g1 = mv > v1, g2 = mv > v2;
        v2  = g1 ? v1  : (g2 ? mv : v2);
        tt2 = g1 ? tt1 : (g2 ? t  : tt2);
        v1  = g0 ? v0  : (g1 ? mv : v1);
        tt1 = g0 ? tt0 : (g1 ? t  : tt1);
        v0  = g0 ? mv  : v0;
        tt0 = g0 ? t   : tt0;
      }
    }
    u64 K0 = ((u64)v0 << 32) | (u64)(0xFFFFFFFFu - tt0);
    u64 K1 = ((u64)v1 << 32) | (u64)(0xFFFFFFFFu - tt1);
    u64 K2 = ((u64)v2 << 32) | (u64)(0xFFFFFFFFu - tt2);
    // merge across the 4 lk-lanes of this lm-group
    u64 p0 = __shfl_xor(K0, 16), p1 = __shfl_xor(K1, 16), p2 = __shfl_xor(K2, 16);
    merge3(K0, K1, K2, p0, p1, p2);
    p0 = __shfl_xor(K0, 32); p1 = __shfl_xor(K1, 32); p2 = __shfl_xor(K2, 32);
    merge3(K0, K1, K2, p0, p1, p2);
    if (lk == 0) {
      int c = fn * 16 + lm;                  // 0..63
      ldsK[(wid * 64 + c) * 3 + 0] = K0;
      ldsK[(wid * 64 + c) * 3 + 1] = K1;
      ldsK[(wid * 64 + c) * 3 + 2] = K2;
    }
  }
  __syncthreads();
  if (wid < 2) {                             // wr==0 waves merge with their wr==1 partner
    int c = lane;                            // 0..63; e = e0 + wid*64 + c  (wid == wc here)
    u64 A0 = ldsK[(wid * 64 + c) * 3 + 0];
    u64 A1 = ldsK[(wid * 64 + c) * 3 + 1];
    u64 A2 = ldsK[(wid * 64 + c) * 3 + 2];
    u64 C0 = ldsK[((wid + 2) * 64 + c) * 3 + 0];
    u64 C1 = ldsK[((wid + 2) * 64 + c) * 3 + 1];
    u64 C2 = ldsK[((wid + 2) * 64 + c) * 3 + 2];
    merge3(A0, A1, A2, C0, C1, C2);
    int eg = e0 + wid * 64 + c;
    size_t R = (size_t)(mtile * 2 + b) * NE_ + (size_t)n * E_ + eg;
    k0g[R] = A0; k1g[R] = A1; k2g[R] = A2;
  }
}

// ---------------- Kernel 3: merge tile records -> global top-3 -> slot scatter ----------------
__global__ __launch_bounds__(256) void merge_scatter2(const u64* __restrict__ k0g,
                                                      const u64* __restrict__ k1g,
                                                      const u64* __restrict__ k2g,
                                                      u64* __restrict__ keys) {
  int gid2 = blockIdx.x * 256 + threadIdx.x;  // 32768 = B*NB*E
  int b  = gid2 >> 14;
  int ne = gid2 & (NE_ - 1);

  u64 K0 = 0, K1 = 0, K2 = 0;
  for (int mt = 0; mt < MT_; ++mt) {
    size_t R = (size_t)(mt * 2 + b) * NE_ + ne;
    merge3(K0, K1, K2, k0g[R], k1g[R], k2g[R]);
  }

  int n = ne >> 12;
  u32 e = (u32)(ne & (E_ - 1));
  u64 elo = (u64)(0xFFFFFFFFu - e);
  u32 t0 = 0xFFFFFFFFu - (u32)K0;
  u32 t1 = 0xFFFFFFFFu - (u32)K1;
  u32 t2 = 0xFFFFFFFFu - (u32)K2;
  atomicMax(&keys[((size_t)b * T_ + t0) * NB_ + n], (K0 & 0xFFFFFFFF00000000ull) | elo);
  atomicMax(&keys[((size_t)b * T_ + t1) * NB_ + n], (K1 & 0xFFFFFFFF00000000ull) | elo);
  atomicMax(&keys[((size_t)b * T_ + t2) * NB_ + n], (K2 & 0xFFFFFFFF00000000ull) | elo);
}

// ---------------- Fallback path (small ws): in-kernel-split GEMM + monolithic select ----------------
__device__ __forceinline__ void split8(const float* __restrict__ p, f16x8 &hi, f16x8 &lo) {
  float4 a0 = *(const float4*)p;
  float4 a1 = *(const float4*)(p + 4);
  split8v(a0, a1, hi, lo);
}

__global__ __launch_bounds__(256) void gemm_logits_fb(const float* __restrict__ x,
                                                      const float* __restrict__ W,
                                                      float* __restrict__ logits) {
  __shared__ f16x8 AhV[128 * 4];
  __shared__ f16x8 AlV[128 * 4];
  __shared__ f16x8 BhV[128 * 4];
  __shared__ f16x8 BlV[128 * 4];

  const int n  = blockIdx.z;
  const int m0 = blockIdx.y * BM;
  const int e0 = blockIdx.x * BN;
  const int tid  = threadIdx.x;
  const int lane = tid & 63;
  const int wid  = tid >> 6;
  const int wr   = wid >> 1;
  const int wc   = wid & 1;
  const int lm   = lane & 15;
  const int lk   = lane >> 4;

  const float* Abase = x + ((size_t)m0 * NB_ + n) * D_;
  const float* Bbase = W + ((size_t)n * E_ + e0) * D_;

  f32x4 acc[4][4];
#pragma unroll
  for (int i = 0; i < 4; ++i)
#pragma unroll
    for (int j = 0; j < 4; ++j) acc[i][j] = (f32x4){0.f, 0.f, 0.f, 0.f};

  for (int k0 = 0; k0 < D_; k0 += 32) {
#pragma unroll
    for (int l = 0; l < 2; ++l) {
      int aid = tid + l * 256;
      int r   = aid >> 2;
      int ko  = aid & 3;
      int ps  = ko ^ ((r >> 1) & 3);
      f16x8 hi, lo;
      split8(Abase + (size_t)r * (NB_ * D_) + k0 + ko * 8, hi, lo);
      AhV[r * 4 + ps] = hi; AlV[r * 4 + ps] = lo;
      split8(Bbase + (size_t)r * D_ + k0 + ko * 8, hi, lo);
      BhV[r * 4 + ps] = hi; BlV[r * 4 + ps] = lo;
    }
    __syncthreads();

    f16x8 bh[4], bl[4];
#pragma unroll
    for (int fn = 0; fn < 4; ++fn) {
      int row = wc * 64 + fn * 16 + lm;
      int ps  = lk ^ ((row >> 1) & 3);
      bh[fn] = BhV[row * 4 + ps];
      bl[fn] = BlV[row * 4 + ps];
    }
#pragma unroll
    for (int fm = 0; fm < 4; ++fm) {
      int row = wr * 64 + fm * 16 + lm;
      int ps  = lk ^ ((row >> 1) & 3);
      f16x8 ah = AhV[row * 4 + ps];
      f16x8 al = AlV[row * 4 + ps];
#pragma unroll
      for (int fn = 0; fn < 4; ++fn) {
        acc[fm][fn] = __builtin_amdgcn_mfma_f32_16x16x32_f16(ah, bh[fn], acc[fm][fn], 0, 0, 0);
        acc[fm][fn] = __builtin_amdgcn_mfma_f32_16x16x32_f16(ah, bl[fn], acc[fm][fn], 0, 0, 0);
        acc[fm][fn] = __builtin_amdgcn_mfma_f32_16x16x32_f16(al, bh[fn], acc[fm][fn], 0, 0, 0);
      }
    }
    __syncthreads();
  }

#pragma unroll
  for (int fm = 0; fm < 4; ++fm) {
#pragma unroll
    for (int fn = 0; fn < 4; ++fn) {
#pragma unroll
      for (int r = 0; r < 4; ++r) {
        int m = m0 + wr * 64 + fm * 16 + lk * 4 + r;
        int e = e0 + wc * 64 + fn * 16 + lm;
        logits[((size_t)m * NB_ + n) * E_ + e] = acc[fm][fn][r] * INV_SC;
      }
    }
  }
}

__global__ __launch_bounds__(256) void select_scatter(const float* __restrict__ logits,
                                                      u64* __restrict__ keys) {
  int gid = blockIdx.x * 256 + threadIdx.x;  // 32768 = B*NB*E
  int b  = gid >> 14;
  int ne = gid & (NE_ - 1);

  float v0 = -1e30f, v1 = -1e30f, v2 = -1e30f;
  int   t0 = 0, t1 = 0, t2 = 0;

  const float* lg = logits + (size_t)b * HALF_;
  const u32 ib = (u32)b * HALF_ + (u32)ne;
  for (int t = 0; t < T_; ++t) {
    u32 i0 = (u32)t * (u32)NE_ + (u32)ne;
    float y = lg[i0] * noise_at(ib + (u32)t * (u32)NE_);
    if (y > v0)      { v2=v1; t2=t1; v1=v0; t1=t0; v0=y; t0=t; }
    else if (y > v1) { v2=v1; t2=t1; v1=y;  t1=t; }
    else if (y > v2) { v2=y;  t2=t; }
  }

  int n = ne >> 12;
  int e = ne & (E_ - 1);
  u64 klo = 0xFFFFFFFFull - (u32)e;
  atomicMax(&keys[((size_t)b * T_ + t0) * NB_ + n], ((u64)map_f32(v0) << 32) | klo);
  atomicMax(&keys[((size_t)b * T_ + t1) * NB_ + n], ((u64)map_f32(v1) << 32) | klo);
  atomicMax(&keys[((size_t)b * T_ + t2) * NB_ + n], ((u64)map_f32(v2) << 32) | klo);
}

// ---------------- Kernel 4: decode argmax -> idx + latent gather ----------------
__global__ __launch_bounds__(128) void finalize(const u64* __restrict__ keys,
                                                const float* __restrict__ W,
                                                float* __restrict__ out_idx,
                                                float* __restrict__ out_lat) {
  int slot = blockIdx.x;                     // (b*T+t)*NB + n
  int n = slot & (NB_ - 1);
  int e = (int)(0xFFFFFFFFu - (u32)keys[slot]) & (E_ - 1);
  if (threadIdx.x == 0) out_idx[slot] = (float)e;

  const float4 v = ((const float4*)(W + ((size_t)n * E_ + e) * D_))[threadIdx.x];
  ((float4*)(out_lat + (size_t)slot * D_))[threadIdx.x] = v;   // 128 x 16B = 2KB
}

// ---------------- Launch ----------------
extern "C" void kernel_launch(void* const* d_in, const int* in_sizes, int n_in,
                              void* d_out, int out_size, void* d_ws, size_t ws_size,
                              hipStream_t stream) {
  const float* x = (const float*)d_in[0];    // [B,T,NB*D] fp32
  const float* W = (const float*)d_in[1];    // [NB,E,D]  fp32

  float* out_idx    = (float*)d_out;                          // 32,768
  float* out_lat    = out_idx + (size_t)SLOTS_;               // 16,777,216
  float* out_logits = out_lat + (size_t)SLOTS_ * D_;          // 134,217,728

  // ws layout: keys | xh | xl | wh | wl
  u64* keys = (u64*)d_ws;
  const size_t KEYS_B = (size_t)SLOTS_ * 8;                   // 256 KiB
  const size_t XH_B   = (size_t)XN8_ * 16;                    // 32 MiB
  const size_t WH_B   = (size_t)WN8_ * 16;                    // 16 MiB
  bool split = ws_size >= KEYS_B + 2 * XH_B + 2 * WH_B;       // ~96.3 MB

  char*  sp = (char*)d_ws + KEYS_B;
  f16x8* xh = (f16x8*)sp;
  f16x8* xl = (f16x8*)(sp + XH_B);
  f16x8* wh = (f16x8*)(sp + 2 * XH_B);
  f16x8* wl = (f16x8*)(sp + 2 * XH_B + WH_B);

  // tile-select records live in the out_lat region (overwritten by finalize later)
  u64* k0g = (u64*)out_lat;                                   // 8 MB each
  u64* k1g = k0g + RECN_;
  u64* k2g = k1g + RECN_;

  init_keys<<<SLOTS_ / 256, 256, 0, stream>>>(keys);

  dim3 ggrid(E_ / BN, (B_ * T_) / BM, NB_);
  if (split) {
    presplit<<<(XN8_ + WN8_) / 256, 256, 0, stream>>>(x, W, xh, xl, wh, wl);
    gemm_fused<<<ggrid, 256, 0, stream>>>(xh, xl, wh, wl, out_logits, k0g, k1g, k2g);
    merge_scatter2<<<SLOTS_ / 256, 256, 0, stream>>>(k0g, k1g, k2g, keys);
  } else {
    gemm_logits_fb<<<ggrid, 256, 0, stream>>>(x, W, out_logits);
    select_scatter<<<SLOTS_ / 256, 256, 0, stream>>>(out_logits, keys);
  }

  finalize<<<SLOTS_, 128, 0, stream>>>(keys, W, out_idx, out_lat);
}

// Round 14
// 738.614 us; speedup vs baseline: 8.8328x; 1.0466x over previous
//
#include <hip/hip_runtime.h>
#include <stdint.h>

// Problem constants
#define B_     2
#define T_     4096
#define NB_    4
#define D_     512
#define E_     4096
#define NE_    16384           // NB*E
#define HALF_  67108864u       // T*NB*E  (per-b flat block of [B,T,NB,E])
#define SLOTS_ 32768           // B*T*NB
#define XN8_   2097152         // B*T*NB*D/8
#define WN8_   1048576         // NB*E*D/8
#define MT_    32              // m-tiles per b = T/128
#define RECN_  (64 * NE_)      // (MT_*B) * NE records per key array

typedef unsigned long long u64;
typedef uint32_t u32;
typedef _Float16 f16x8 __attribute__((ext_vector_type(8)));
typedef float    f32x4 __attribute__((ext_vector_type(4)));

// ---------------- Threefry-2x32-20, key = (0, 42) ----------------
__device__ __forceinline__ u32 rotl32(u32 x, int r) { return __builtin_rotateleft32(x, r); }

__device__ __forceinline__ void tf_0_42(u32 x0, u32 x1, u32 &o0, u32 &o1) {
  const u32 ks0 = 0u, ks1 = 42u, ks2 = 0x1BD11BDAu ^ 0u ^ 42u;
  x0 += ks0; x1 += ks1;
#define TFR(r) { x0 += x1; x1 = rotl32(x1, (r)); x1 ^= x0; }
  TFR(13) TFR(15) TFR(26) TFR(6)
  x0 += ks1; x1 += ks2 + 1u;
  TFR(17) TFR(29) TFR(16) TFR(24)
  x0 += ks2; x1 += ks0 + 2u;
  TFR(13) TFR(15) TFR(26) TFR(6)
  x0 += ks0; x1 += ks1 + 3u;
  TFR(17) TFR(29) TFR(16) TFR(24)
  x0 += ks1; x1 += ks2 + 4u;
  TFR(13) TFR(15) TFR(26) TFR(6)
  x0 += ks2; x1 += ks0 + 5u;
#undef TFR
  o0 = x0; o1 = x1;
}

// Partitionable noise (VERIFIED R7): XOR fold o0^o1 of threefry(key,(0,i))
__device__ __forceinline__ float noise_at(u32 i) {
  u32 o0, o1; tf_0_42(0u, i, o0, o1);
  u32 bits = o0 ^ o1;
  float f = __uint_as_float((bits >> 9) | 0x3F800000u);  // [1,2)
  return 2.0f - f;                                        // 1 - uniform
}

// order-preserving map fp32 -> u32, branchless (finite inputs)
__device__ __forceinline__ u32 map_f32(float v) {
  u32 u = __float_as_uint(v);
  u32 s = (u32)((int)u >> 31);               // 0 or 0xFFFFFFFF
  return u ^ (s | 0x80000000u);
}

// merge two sorted-desc key triples: (a0>=a1>=a2) <- top3 of {a*, b*}
__device__ __forceinline__ void merge3(u64 &a0, u64 &a1, u64 &a2,
                                       u64 b0, u64 b1, u64 b2) {
  u64 o0, o1, o2;
  if (a0 >= b0) {
    o0 = a0;
    if (a1 >= b0) { o1 = a1; o2 = (a2 >= b0) ? a2 : b0; }
    else          { o1 = b0; o2 = (a1 >= b1) ? a1 : b1; }
  } else {
    o0 = b0;
    if (b1 >= a0) { o1 = b1; o2 = (b2 >= a0) ? b2 : a0; }
    else          { o1 = a0; o2 = (b1 >= a1) ? b1 : a1; }
  }
  a0 = o0; a1 = o1; a2 = o2;
}

#define BASE_KEY 0x80000000FFFFFFFFull   // (+0.0, e=0): empty slot -> argmax 0
#define SCALE_   2048.0f
#define INV_SC   (1.0f / 4194304.0f)     // 2^-22

// ---------------- Kernel 1: init keys + prune thresholds ----------------
__global__ __launch_bounds__(256) void init_keys(u64* __restrict__ keys,
                                                 u32* __restrict__ thr) {
  int i = blockIdx.x * 256 + threadIdx.x;    // 32768
  keys[i] = BASE_KEY;
  thr[i]  = 0u;
}

// ---------------- Kernel 1b: pre-split fp32 -> (hi,lo) fp16, scaled by 2^11 ----------------
__device__ __forceinline__ void split8v(const float4 a0, const float4 a1, f16x8 &hi, f16x8 &lo) {
  float fv[8] = {a0.x, a0.y, a0.z, a0.w, a1.x, a1.y, a1.z, a1.w};
#pragma unroll
  for (int j = 0; j < 8; ++j) {
    float f = fv[j] * SCALE_;
    _Float16 h = (_Float16)f;
    hi[j] = h;
    lo[j] = (_Float16)(f - (float)h);
  }
}

__global__ __launch_bounds__(256) void presplit(const float* __restrict__ x,
                                                const float* __restrict__ W,
                                                f16x8* __restrict__ xh, f16x8* __restrict__ xl,
                                                f16x8* __restrict__ wh, f16x8* __restrict__ wl) {
  size_t g = (size_t)blockIdx.x * 256 + threadIdx.x;   // unit = 8 floats
  const float4* src;
  f16x8 *dh, *dl;
  size_t off;
  if (g < XN8_) { src = (const float4*)x; dh = xh; dl = xl; off = g; }
  else          { src = (const float4*)W; dh = wh; dl = wl; off = g - XN8_; }
  float4 a0 = src[off * 2], a1 = src[off * 2 + 1];
  f16x8 hi, lo;
  split8v(a0, a1, hi, lo);
  dh[off] = hi; dl[off] = lo;
}

// ---------------- Kernel 2: fused GEMM + pruned noisy top-3 select ----------------
#define BM 128
#define BN 128

__global__ __launch_bounds__(256) void gemm_fused(const f16x8* __restrict__ xh,
                                                  const f16x8* __restrict__ xl,
                                                  const f16x8* __restrict__ wh,
                                                  const f16x8* __restrict__ wl,
                                                  float* __restrict__ logits,
                                                  u64* __restrict__ k0g,
                                                  u64* __restrict__ k1g,
                                                  u64* __restrict__ k2g,
                                                  u32* __restrict__ thrbuf) {
  __shared__ f16x8 AhV[128 * 4];
  __shared__ f16x8 AlV[128 * 4];
  __shared__ f16x8 BhV[128 * 4];
  __shared__ f16x8 BlV[128 * 4];

  const int n  = blockIdx.z;
  const int m0 = blockIdx.y * BM;            // m = b*T + t
  const int e0 = blockIdx.x * BN;
  const int tid  = threadIdx.x;
  const int lane = tid & 63;
  const int wid  = tid >> 6;                 // 4 waves: wid = wr*2 + wc
  const int wr   = wid >> 1;
  const int wc   = wid & 1;
  const int lm   = lane & 15;
  const int lk   = lane >> 4;                // k-group 0..3

  f32x4 acc[4][4];
#pragma unroll
  for (int i = 0; i < 4; ++i)
#pragma unroll
    for (int j = 0; j < 4; ++j) acc[i][j] = (f32x4){0.f, 0.f, 0.f, 0.f};

  for (int k0 = 0; k0 < D_ / 8; k0 += 4) {   // K-step = 32 halfs = 4 groups
#pragma unroll
    for (int l = 0; l < 2; ++l) {
      int aid = tid + l * 256;               // 0..511
      int r   = aid >> 2;                    // 0..127 (tile row)
      int ko  = aid & 3;                     // k-group
      int ps  = ko ^ ((r >> 1) & 3);         // swizzled slot
      size_t gA = ((size_t)(m0 + r) * NB_ + n) * (D_ / 8) + k0 + ko;
      AhV[r * 4 + ps] = xh[gA];
      AlV[r * 4 + ps] = xl[gA];
      size_t gB = ((size_t)n * E_ + e0 + r) * (D_ / 8) + k0 + ko;
      BhV[r * 4 + ps] = wh[gB];
      BlV[r * 4 + ps] = wl[gB];
    }
    __syncthreads();

    f16x8 bh[4], bl[4];
#pragma unroll
    for (int fn = 0; fn < 4; ++fn) {
      int row = wc * 64 + fn * 16 + lm;
      int ps  = lk ^ ((row >> 1) & 3);
      bh[fn] = BhV[row * 4 + ps];
      bl[fn] = BlV[row * 4 + ps];
    }
#pragma unroll
    for (int fm = 0; fm < 4; ++fm) {
      int row = wr * 64 + fm * 16 + lm;
      int ps  = lk ^ ((row >> 1) & 3);
      f16x8 ah = AhV[row * 4 + ps];
      f16x8 al = AlV[row * 4 + ps];
#pragma unroll
      for (int fn = 0; fn < 4; ++fn) {
        acc[fm][fn] = __builtin_amdgcn_mfma_f32_16x16x32_f16(ah, bh[fn], acc[fm][fn], 0, 0, 0);
        acc[fm][fn] = __builtin_amdgcn_mfma_f32_16x16x32_f16(ah, bl[fn], acc[fm][fn], 0, 0, 0);
        acc[fm][fn] = __builtin_amdgcn_mfma_f32_16x16x32_f16(al, bh[fn], acc[fm][fn], 0, 0, 0);
      }
    }
    __syncthreads();
  }

  // ---- epilogue part 1: store logits ----
  const int b     = m0 >> 12;                // m0 / T_
  const int mbase = m0 & (T_ - 1);           // t of tile row 0
  const int mtile = mbase >> 7;

#pragma unroll
  for (int fm = 0; fm < 4; ++fm) {
#pragma unroll
    for (int r = 0; r < 4; ++r) {
      int m = m0 + wr * 64 + fm * 16 + lk * 4 + r;
      float* row = logits + ((size_t)m * NB_ + n) * E_ + e0 + wc * 64 + lm;
#pragma unroll
      for (int fn = 0; fn < 4; ++fn) row[fn * 16] = acc[fm][fn][r] * INV_SC;
    }
  }

  // ---- epilogue part 2: pruned per-column noisy top-3 ----
  // Prune rule (exact): y = lg*(2-f) <= ub = max(lg,0).  Skip an element iff
  //   map(ub) <  thr      (thr = some evaluated subset's 3rd-max -> y < v2_final strictly), or
  //   map(ub) <= v2_local (equivalent to the insert's strict-> rejection).
  // thr only grows (atomicMax); stale reads are safe (less pruning, never wrong).
  u64* ldsK = (u64*)AhV;                     // repurposed: [4 waves][64 cols][3] u64 = 6 KB

#pragma unroll
  for (int fn = 0; fn < 4; ++fn) {
    const int e  = e0 + wc * 64 + fn * 16 + lm;   // e within [0,E)
    const int ne = n * E_ + e;
    const u32 thrv = thrbuf[(size_t)b * NE_ + ne];
    u32 v0 = 0, v1 = 0, v2 = 0;                   // mapped y values
    u32 tt0 = 0, tt1 = 0, tt2 = 0;
    const u32 ibase = (u32)b * HALF_ + (u32)ne;
#pragma unroll
    for (int fm = 0; fm < 4; ++fm) {              // t ascends within thread
#pragma unroll
      for (int r = 0; r < 4; ++r) {
        const u32 t = (u32)(mbase + wr * 64 + fm * 16 + lk * 4 + r);
        float lg = acc[fm][fn][r] * INV_SC;
        u32 mu = __float_as_uint(fmaxf(lg, 0.0f)) | 0x80000000u;   // map(ub), ub >= 0
        u32 gate = v2 + 1u;                        // eval iff mu > v2 ...
        gate = gate > thrv ? gate : thrv;          // ... and mu >= thrv
        if (mu >= gate) {
          float y = lg * noise_at(ibase + t * (u32)NE_);
          u32 mv = map_f32(y);
          bool g0 = mv > v0, g1 = mv > v1, g2 = mv > v2;
          v2  = g1 ? v1  : (g2 ? mv : v2);
          tt2 = g1 ? tt1 : (g2 ? t  : tt2);
          v1  = g0 ? v0  : (g1 ? mv : v1);
          tt1 = g0 ? tt0 : (g1 ? t  : tt1);
          v0  = g0 ? mv  : v0;
          tt0 = g0 ? t   : tt0;
        }
      }
    }
    u64 K0 = ((u64)v0 << 32) | (u64)(0xFFFFFFFFu - tt0);
    u64 K1 = ((u64)v1 << 32) | (u64)(0xFFFFFFFFu - tt1);
    u64 K2 = ((u64)v2 << 32) | (u64)(0xFFFFFFFFu - tt2);
    // merge across the 4 lk-lanes of this lm-group
    u64 p0 = __shfl_xor(K0, 16), p1 = __shfl_xor(K1, 16), p2 = __shfl_xor(K2, 16);
    merge3(K0, K1, K2, p0, p1, p2);
    p0 = __shfl_xor(K0, 32); p1 = __shfl_xor(K1, 32); p2 = __shfl_xor(K2, 32);
    merge3(K0, K1, K2, p0, p1, p2);
    if (lk == 0) {
      int c = fn * 16 + lm;                  // 0..63
      ldsK[(wid * 64 + c) * 3 + 0] = K0;
      ldsK[(wid * 64 + c) * 3 + 1] = K1;
      ldsK[(wid * 64 + c) * 3 + 2] = K2;
    }
  }
  __syncthreads();
  if (wid < 2) {                             // wr==0 waves merge with their wr==1 partner
    int c = lane;                            // 0..63; e = e0 + wid*64 + c  (wid == wc here)
    u64 A0 = ldsK[(wid * 64 + c) * 3 + 0];
    u64 A1 = ldsK[(wid * 64 + c) * 3 + 1];
    u64 A2 = ldsK[(wid * 64 + c) * 3 + 2];
    u64 C0 = ldsK[((wid + 2) * 64 + c) * 3 + 0];
    u64 C1 = ldsK[((wid + 2) * 64 + c) * 3 + 1];
    u64 C2 = ldsK[((wid + 2) * 64 + c) * 3 + 2];
    merge3(A0, A1, A2, C0, C1, C2);
    int eg = e0 + wid * 64 + c;
    size_t R = (size_t)(mtile * 2 + b) * NE_ + (size_t)n * E_ + eg;
    k0g[R] = A0; k1g[R] = A1; k2g[R] = A2;
    // publish this tile's evaluated-subset 3rd-max as a prune threshold
    atomicMax(&thrbuf[(size_t)b * NE_ + (size_t)n * E_ + eg], (u32)(A2 >> 32));
  }
}

// ---------------- Kernel 3: merge tile records -> global top-3 -> slot scatter ----------------
__global__ __launch_bounds__(256) void merge_scatter2(const u64* __restrict__ k0g,
                                                      const u64* __restrict__ k1g,
                                                      const u64* __restrict__ k2g,
                                                      u64* __restrict__ keys) {
  int gid2 = blockIdx.x * 256 + threadIdx.x;  // 32768 = B*NB*E
  int b  = gid2 >> 14;
  int ne = gid2 & (NE_ - 1);

  u64 K0 = 0, K1 = 0, K2 = 0;
  for (int mt = 0; mt < MT_; ++mt) {
    size_t R = (size_t)(mt * 2 + b) * NE_ + ne;
    merge3(K0, K1, K2, k0g[R], k1g[R], k2g[R]);
  }

  int n = ne >> 12;
  u32 e = (u32)(ne & (E_ - 1));
  u64 elo = (u64)(0xFFFFFFFFu - e);
  u32 t0 = 0xFFFFFFFFu - (u32)K0;
  u32 t1 = 0xFFFFFFFFu - (u32)K1;
  u32 t2 = 0xFFFFFFFFu - (u32)K2;
  atomicMax(&keys[((size_t)b * T_ + t0) * NB_ + n], (K0 & 0xFFFFFFFF00000000ull) | elo);
  atomicMax(&keys[((size_t)b * T_ + t1) * NB_ + n], (K1 & 0xFFFFFFFF00000000ull) | elo);
  atomicMax(&keys[((size_t)b * T_ + t2) * NB_ + n], (K2 & 0xFFFFFFFF00000000ull) | elo);
}

// ---------------- Fallback path (small ws): in-kernel-split GEMM + monolithic select ----------------
__device__ __forceinline__ void split8(const float* __restrict__ p, f16x8 &hi, f16x8 &lo) {
  float4 a0 = *(const float4*)p;
  float4 a1 = *(const float4*)(p + 4);
  split8v(a0, a1, hi, lo);
}

__global__ __launch_bounds__(256) void gemm_logits_fb(const float* __restrict__ x,
                                                      const float* __restrict__ W,
                                                      float* __restrict__ logits) {
  __shared__ f16x8 AhV[128 * 4];
  __shared__ f16x8 AlV[128 * 4];
  __shared__ f16x8 BhV[128 * 4];
  __shared__ f16x8 BlV[128 * 4];

  const int n  = blockIdx.z;
  const int m0 = blockIdx.y * BM;
  const int e0 = blockIdx.x * BN;
  const int tid  = threadIdx.x;
  const int lane = tid & 63;
  const int wid  = tid >> 6;
  const int wr   = wid >> 1;
  const int wc   = wid & 1;
  const int lm   = lane & 15;
  const int lk   = lane >> 4;

  const float* Abase = x + ((size_t)m0 * NB_ + n) * D_;
  const float* Bbase = W + ((size_t)n * E_ + e0) * D_;

  f32x4 acc[4][4];
#pragma unroll
  for (int i = 0; i < 4; ++i)
#pragma unroll
    for (int j = 0; j < 4; ++j) acc[i][j] = (f32x4){0.f, 0.f, 0.f, 0.f};

  for (int k0 = 0; k0 < D_; k0 += 32) {
#pragma unroll
    for (int l = 0; l < 2; ++l) {
      int aid = tid + l * 256;
      int r   = aid >> 2;
      int ko  = aid & 3;
      int ps  = ko ^ ((r >> 1) & 3);
      f16x8 hi, lo;
      split8(Abase + (size_t)r * (NB_ * D_) + k0 + ko * 8, hi, lo);
      AhV[r * 4 + ps] = hi; AlV[r * 4 + ps] = lo;
      split8(Bbase + (size_t)r * D_ + k0 + ko * 8, hi, lo);
      BhV[r * 4 + ps] = hi; BlV[r * 4 + ps] = lo;
    }
    __syncthreads();

    f16x8 bh[4], bl[4];
#pragma unroll
    for (int fn = 0; fn < 4; ++fn) {
      int row = wc * 64 + fn * 16 + lm;
      int ps  = lk ^ ((row >> 1) & 3);
      bh[fn] = BhV[row * 4 + ps];
      bl[fn] = BlV[row * 4 + ps];
    }
#pragma unroll
    for (int fm = 0; fm < 4; ++fm) {
      int row = wr * 64 + fm * 16 + lm;
      int ps  = lk ^ ((row >> 1) & 3);
      f16x8 ah = AhV[row * 4 + ps];
      f16x8 al = AlV[row * 4 + ps];
#pragma unroll
      for (int fn = 0; fn < 4; ++fn) {
        acc[fm][fn] = __builtin_amdgcn_mfma_f32_16x16x32_f16(ah, bh[fn], acc[fm][fn], 0, 0, 0);
        acc[fm][fn] = __builtin_amdgcn_mfma_f32_16x16x32_f16(ah, bl[fn], acc[fm][fn], 0, 0, 0);
        acc[fm][fn] = __builtin_amdgcn_mfma_f32_16x16x32_f16(al, bh[fn], acc[fm][fn], 0, 0, 0);
      }
    }
    __syncthreads();
  }

#pragma unroll
  for (int fm = 0; fm < 4; ++fm) {
#pragma unroll
    for (int fn = 0; fn < 4; ++fn) {
#pragma unroll
      for (int r = 0; r < 4; ++r) {
        int m = m0 + wr * 64 + fm * 16 + lk * 4 + r;
        int e = e0 + wc * 64 + fn * 16 + lm;
        logits[((size_t)m * NB_ + n) * E_ + e] = acc[fm][fn][r] * INV_SC;
      }
    }
  }
}

__global__ __launch_bounds__(256) void select_scatter(const float* __restrict__ logits,
                                                      u64* __restrict__ keys) {
  int gid = blockIdx.x * 256 + threadIdx.x;  // 32768 = B*NB*E
  int b  = gid >> 14;
  int ne = gid & (NE_ - 1);

  float v0 = -1e30f, v1 = -1e30f, v2 = -1e30f;
  int   t0 = 0, t1 = 0, t2 = 0;

  const float* lg = logits + (size_t)b * HALF_;
  const u32 ib = (u32)b * HALF_ + (u32)ne;
  for (int t = 0; t < T_; ++t) {
    u32 i0 = (u32)t * (u32)NE_ + (u32)ne;
    float y = lg[i0] * noise_at(ib + (u32)t * (u32)NE_);
    if (y > v0)      { v2=v1; t2=t1; v1=v0; t1=t0; v0=y; t0=t; }
    else if (y > v1) { v2=v1; t2=t1; v1=y;  t1=t; }
    else if (y > v2) { v2=y;  t2=t; }
  }

  int n = ne >> 12;
  int e = ne & (E_ - 1);
  u64 klo = 0xFFFFFFFFull - (u32)e;
  atomicMax(&keys[((size_t)b * T_ + t0) * NB_ + n], ((u64)map_f32(v0) << 32) | klo);
  atomicMax(&keys[((size_t)b * T_ + t1) * NB_ + n], ((u64)map_f32(v1) << 32) | klo);
  atomicMax(&keys[((size_t)b * T_ + t2) * NB_ + n], ((u64)map_f32(v2) << 32) | klo);
}

// ---------------- Kernel 4: decode argmax -> idx + latent gather ----------------
__global__ __launch_bounds__(128) void finalize(const u64* __restrict__ keys,
                                                const float* __restrict__ W,
                                                float* __restrict__ out_idx,
                                                float* __restrict__ out_lat) {
  int slot = blockIdx.x;                     // (b*T+t)*NB + n
  int n = slot & (NB_ - 1);
  int e = (int)(0xFFFFFFFFu - (u32)keys[slot]) & (E_ - 1);
  if (threadIdx.x == 0) out_idx[slot] = (float)e;

  const float4 v = ((const float4*)(W + ((size_t)n * E_ + e) * D_))[threadIdx.x];
  ((float4*)(out_lat + (size_t)slot * D_))[threadIdx.x] = v;   // 128 x 16B = 2KB
}

// ---------------- Launch ----------------
extern "C" void kernel_launch(void* const* d_in, const int* in_sizes, int n_in,
                              void* d_out, int out_size, void* d_ws, size_t ws_size,
                              hipStream_t stream) {
  const float* x = (const float*)d_in[0];    // [B,T,NB*D] fp32
  const float* W = (const float*)d_in[1];    // [NB,E,D]  fp32

  float* out_idx    = (float*)d_out;                          // 32,768
  float* out_lat    = out_idx + (size_t)SLOTS_;               // 16,777,216
  float* out_logits = out_lat + (size_t)SLOTS_ * D_;          // 134,217,728

  // ws layout: keys | thr | xh | xl | wh | wl
  u64* keys = (u64*)d_ws;
  const size_t KEYS_B = (size_t)SLOTS_ * 8;                   // 256 KiB
  const size_t THR_B  = (size_t)SLOTS_ * 4;                   // 128 KiB
  const size_t XH_B   = (size_t)XN8_ * 16;                    // 32 MiB
  const size_t WH_B   = (size_t)WN8_ * 16;                    // 16 MiB
  bool split = ws_size >= KEYS_B + THR_B + 2 * XH_B + 2 * WH_B;

  u32*   thr = (u32*)((char*)d_ws + KEYS_B);
  char*  sp  = (char*)d_ws + KEYS_B + THR_B;
  f16x8* xh  = (f16x8*)sp;
  f16x8* xl  = (f16x8*)(sp + XH_B);
  f16x8* wh  = (f16x8*)(sp + 2 * XH_B);
  f16x8* wl  = (f16x8*)(sp + 2 * XH_B + WH_B);

  // tile-select records live in the out_lat region (overwritten by finalize later)
  u64* k0g = (u64*)out_lat;                                   // 8 MB each
  u64* k1g = k0g + RECN_;
  u64* k2g = k1g + RECN_;

  init_keys<<<SLOTS_ / 256, 256, 0, stream>>>(keys, thr);

  dim3 ggrid(E_ / BN, (B_ * T_) / BM, NB_);
  if (split) {
    presplit<<<(XN8_ + WN8_) / 256, 256, 0, stream>>>(x, W, xh, xl, wh, wl);
    gemm_fused<<<ggrid, 256, 0, stream>>>(xh, xl, wh, wl, out_logits, k0g, k1g, k2g, thr);
    merge_scatter2<<<SLOTS_ / 256, 256, 0, stream>>>(k0g, k1g, k2g, keys);
  } else {
    gemm_logits_fb<<<ggrid, 256, 0, stream>>>(x, W, out_logits);
    select_scatter<<<SLOTS_ / 256, 256, 0, stream>>>(out_logits, keys);
  }

  finalize<<<SLOTS_, 128, 0, stream>>>(keys, W, out_idx, out_lat);
}

// Round 15
// 698.967 us; speedup vs baseline: 9.3338x; 1.0567x over previous
//
#include <hip/hip_runtime.h>
#include <stdint.h>

// Problem constants
#define B_     2
#define T_     4096
#define NB_    4
#define D_     512
#define E_     4096
#define NE_    16384           // NB*E
#define HALF_  67108864u       // T*NB*E  (per-b flat block of [B,T,NB,E])
#define SLOTS_ 32768           // B*T*NB
#define XN8_   2097152         // B*T*NB*D/8
#define WN8_   1048576         // NB*E*D/8
#define MT_    32              // m-tiles per b = T/128
#define RECN_  (64 * NE_)      // (MT_*B) * NE records per key array

typedef unsigned long long u64;
typedef uint32_t u32;
typedef uint16_t u16;
typedef _Float16 f16x8 __attribute__((ext_vector_type(8)));
typedef float    f32x4 __attribute__((ext_vector_type(4)));

// ---------------- Threefry-2x32-20, key = (0, 42) ----------------
__device__ __forceinline__ u32 rotl32(u32 x, int r) { return __builtin_rotateleft32(x, r); }

__device__ __forceinline__ void tf_0_42(u32 x0, u32 x1, u32 &o0, u32 &o1) {
  const u32 ks0 = 0u, ks1 = 42u, ks2 = 0x1BD11BDAu ^ 0u ^ 42u;
  x0 += ks0; x1 += ks1;
#define TFR(r) { x0 += x1; x1 = rotl32(x1, (r)); x1 ^= x0; }
  TFR(13) TFR(15) TFR(26) TFR(6)
  x0 += ks1; x1 += ks2 + 1u;
  TFR(17) TFR(29) TFR(16) TFR(24)
  x0 += ks2; x1 += ks0 + 2u;
  TFR(13) TFR(15) TFR(26) TFR(6)
  x0 += ks0; x1 += ks1 + 3u;
  TFR(17) TFR(29) TFR(16) TFR(24)
  x0 += ks1; x1 += ks2 + 4u;
  TFR(13) TFR(15) TFR(26) TFR(6)
  x0 += ks2; x1 += ks0 + 5u;
#undef TFR
  o0 = x0; o1 = x1;
}

// Partitionable noise (VERIFIED R7): XOR fold o0^o1 of threefry(key,(0,i))
__device__ __forceinline__ float noise_at(u32 i) {
  u32 o0, o1; tf_0_42(0u, i, o0, o1);
  u32 bits = o0 ^ o1;
  float f = __uint_as_float((bits >> 9) | 0x3F800000u);  // [1,2)
  return 2.0f - f;                                        // 1 - uniform
}

// order-preserving map fp32 -> u32, branchless (finite inputs)
__device__ __forceinline__ u32 map_f32(float v) {
  u32 u = __float_as_uint(v);
  u32 s = (u32)((int)u >> 31);               // 0 or 0xFFFFFFFF
  return u ^ (s | 0x80000000u);
}

// merge two sorted-desc key triples: (a0>=a1>=a2) <- top3 of {a*, b*}
__device__ __forceinline__ void merge3(u64 &a0, u64 &a1, u64 &a2,
                                       u64 b0, u64 b1, u64 b2) {
  u64 o0, o1, o2;
  if (a0 >= b0) {
    o0 = a0;
    if (a1 >= b0) { o1 = a1; o2 = (a2 >= b0) ? a2 : b0; }
    else          { o1 = b0; o2 = (a1 >= b1) ? a1 : b1; }
  } else {
    o0 = b0;
    if (b1 >= a0) { o1 = b1; o2 = (b2 >= a0) ? b2 : a0; }
    else          { o1 = a0; o2 = (b1 >= a1) ? b1 : a1; }
  }
  a0 = o0; a1 = o1; a2 = o2;
}

#define BASE_KEY 0x80000000FFFFFFFFull   // (+0.0, e=0): empty slot -> argmax 0
#define SCALE_   2048.0f
#define INV_SC   (1.0f / 4194304.0f)     // 2^-22

// ---------------- Kernel 1: init keys + prune thresholds ----------------
__global__ __launch_bounds__(256) void init_keys(u64* __restrict__ keys,
                                                 u32* __restrict__ thr) {
  int i = blockIdx.x * 256 + threadIdx.x;    // 32768
  keys[i] = BASE_KEY;
  thr[i]  = 0u;
}

// ---------------- Kernel 1b: pre-split fp32 -> (hi,lo) fp16, scaled by 2^11 ----------------
__device__ __forceinline__ void split8v(const float4 a0, const float4 a1, f16x8 &hi, f16x8 &lo) {
  float fv[8] = {a0.x, a0.y, a0.z, a0.w, a1.x, a1.y, a1.z, a1.w};
#pragma unroll
  for (int j = 0; j < 8; ++j) {
    float f = fv[j] * SCALE_;
    _Float16 h = (_Float16)f;
    hi[j] = h;
    lo[j] = (_Float16)(f - (float)h);
  }
}

__global__ __launch_bounds__(256) void presplit(const float* __restrict__ x,
                                                const float* __restrict__ W,
                                                f16x8* __restrict__ xh, f16x8* __restrict__ xl,
                                                f16x8* __restrict__ wh, f16x8* __restrict__ wl) {
  size_t g = (size_t)blockIdx.x * 256 + threadIdx.x;   // unit = 8 floats
  const float4* src;
  f16x8 *dh, *dl;
  size_t off;
  if (g < XN8_) { src = (const float4*)x; dh = xh; dl = xl; off = g; }
  else          { src = (const float4*)W; dh = wh; dl = wl; off = g - XN8_; }
  float4 a0 = src[off * 2], a1 = src[off * 2 + 1];
  f16x8 hi, lo;
  split8v(a0, a1, hi, lo);
  dh[off] = hi; dl[off] = lo;
}

// ---------------- Kernel 2: fused GEMM + compacted pruned noisy top-3 select ----------------
#define BM 128
#define BN 128

__global__ __launch_bounds__(256) void gemm_fused(const f16x8* __restrict__ xh,
                                                  const f16x8* __restrict__ xl,
                                                  const f16x8* __restrict__ wh,
                                                  const f16x8* __restrict__ wl,
                                                  float* __restrict__ logits,
                                                  u64* __restrict__ k0g,
                                                  u64* __restrict__ k1g,
                                                  u64* __restrict__ k2g,
                                                  u32* __restrict__ thrbuf) {
  __shared__ f16x8 lds_raw[2048];            // 32 KB, repurposed across phases
  f16x8* AhV = lds_raw;                      // K-loop layout
  f16x8* AlV = lds_raw + 512;
  f16x8* BhV = lds_raw + 1024;
  f16x8* BlV = lds_raw + 1536;

  // 1-D grid decode: same-column tiles spaced 128 ids apart (thr warm-up)
  const int id = blockIdx.x;
  const int e0 = (id & 31) * BN;
  const int n  = (id >> 5) & 3;
  const int mt = id >> 7;                    // 0..63
  const int m0 = mt * BM;                    // m = b*T + t

  const int tid  = threadIdx.x;
  const int lane = tid & 63;
  const int wid  = tid >> 6;                 // 4 waves: wid = wr*2 + wc
  const int wr   = wid >> 1;
  const int wc   = wid & 1;
  const int lm   = lane & 15;
  const int lk   = lane >> 4;                // k-group 0..3

  f32x4 acc[4][4];
#pragma unroll
  for (int i = 0; i < 4; ++i)
#pragma unroll
    for (int j = 0; j < 4; ++j) acc[i][j] = (f32x4){0.f, 0.f, 0.f, 0.f};

  for (int k0 = 0; k0 < D_ / 8; k0 += 4) {   // K-step = 32 halfs = 4 groups
#pragma unroll
    for (int l = 0; l < 2; ++l) {
      int aid = tid + l * 256;               // 0..511
      int r   = aid >> 2;                    // 0..127 (tile row)
      int ko  = aid & 3;                     // k-group
      int ps  = ko ^ ((r >> 1) & 3);         // swizzled slot
      size_t gA = ((size_t)(m0 + r) * NB_ + n) * (D_ / 8) + k0 + ko;
      AhV[r * 4 + ps] = xh[gA];
      AlV[r * 4 + ps] = xl[gA];
      size_t gB = ((size_t)n * E_ + e0 + r) * (D_ / 8) + k0 + ko;
      BhV[r * 4 + ps] = wh[gB];
      BlV[r * 4 + ps] = wl[gB];
    }
    __syncthreads();

    f16x8 bh[4], bl[4];
#pragma unroll
    for (int fn = 0; fn < 4; ++fn) {
      int row = wc * 64 + fn * 16 + lm;
      int ps  = lk ^ ((row >> 1) & 3);
      bh[fn] = BhV[row * 4 + ps];
      bl[fn] = BlV[row * 4 + ps];
    }
#pragma unroll
    for (int fm = 0; fm < 4; ++fm) {
      int row = wr * 64 + fm * 16 + lm;
      int ps  = lk ^ ((row >> 1) & 3);
      f16x8 ah = AhV[row * 4 + ps];
      f16x8 al = AlV[row * 4 + ps];
#pragma unroll
      for (int fn = 0; fn < 4; ++fn) {
        acc[fm][fn] = __builtin_amdgcn_mfma_f32_16x16x32_f16(ah, bh[fn], acc[fm][fn], 0, 0, 0);
        acc[fm][fn] = __builtin_amdgcn_mfma_f32_16x16x32_f16(ah, bl[fn], acc[fm][fn], 0, 0, 0);
        acc[fm][fn] = __builtin_amdgcn_mfma_f32_16x16x32_f16(al, bh[fn], acc[fm][fn], 0, 0, 0);
      }
    }
    __syncthreads();
  }
  // After the final barrier all K-loop LDS reads are done -> repurpose LDS:
  float* lgbuf = (float*)lds_raw;                    // 16 KB: [16 slots][256 threads]
  u16*   tbuf  = (u16*)((char*)lds_raw + 16384);     //  8 KB: [16 slots][256 threads]
  u64*   ldsK  = (u64*)((char*)lds_raw + 24576);     //  6 KB: [4 waves][64 cols][3]

  // ---- epilogue part 1: store logits ----
  const int b     = m0 >> 12;                // m0 / T_
  const int mbase = m0 & (T_ - 1);           // t of tile row 0
  const int mtile = mbase >> 7;

#pragma unroll
  for (int fm = 0; fm < 4; ++fm) {
#pragma unroll
    for (int r = 0; r < 4; ++r) {
      int m = m0 + wr * 64 + fm * 16 + lk * 4 + r;
      float* row = logits + ((size_t)m * NB_ + n) * E_ + e0 + wc * 64 + lm;
#pragma unroll
      for (int fn = 0; fn < 4; ++fn) row[fn * 16] = acc[fm][fn][r] * INV_SC;
    }
  }

  // ---- epilogue part 2: compacted pruned per-column noisy top-3 ----
  // Gate (exact): y <= ub = max(lg,0); skip iff map(ub) < thr (thr = subset 3rd-max,
  // monotone via atomicMax; stale reads only reduce pruning, never wrongness).
#pragma unroll
  for (int fn = 0; fn < 4; ++fn) {
    const int e  = e0 + wc * 64 + fn * 16 + lm;   // e within [0,E)
    const int ne = n * E_ + e;
    const u32 thrv = thrbuf[(size_t)b * NE_ + ne];

    // pass 1: compact candidates (lg, t) into LDS
    int cnt = 0;
#pragma unroll
    for (int fm = 0; fm < 4; ++fm) {              // t ascends per lane
#pragma unroll
      for (int r = 0; r < 4; ++r) {
        float lg = acc[fm][fn][r] * INV_SC;
        u32 mu = __float_as_uint(fmaxf(lg, 0.0f)) | 0x80000000u;   // map(ub)
        if (mu >= thrv) {
          lgbuf[cnt * 256 + tid] = lg;
          tbuf [cnt * 256 + tid] = (u16)(mbase + wr * 64 + fm * 16 + lk * 4 + r);
          ++cnt;
        }
      }
    }

    // pass 2: evaluate candidates (wave runs max(cnt) iterations)
    u32 v0 = 0, v1 = 0, v2 = 0;
    u32 tt0 = 0, tt1 = 0, tt2 = 0;
    const u32 ibase = (u32)b * HALF_ + (u32)ne;
    for (int k = 0; k < cnt; ++k) {
      float lg = lgbuf[k * 256 + tid];
      u32 t    = (u32)tbuf[k * 256 + tid];
      float y  = lg * noise_at(ibase + t * (u32)NE_);
      u32 mv = map_f32(y);
      bool g0 = mv > v0, g1 = mv > v1, g2 = mv > v2;
      v2  = g1 ? v1  : (g2 ? mv : v2);
      tt2 = g1 ? tt1 : (g2 ? t  : tt2);
      v1  = g0 ? v0  : (g1 ? mv : v1);
      tt1 = g0 ? tt0 : (g1 ? t  : tt1);
      v0  = g0 ? mv  : v0;
      tt0 = g0 ? t   : tt0;
    }

    u64 K0 = ((u64)v0 << 32) | (u64)(0xFFFFFFFFu - tt0);
    u64 K1 = ((u64)v1 << 32) | (u64)(0xFFFFFFFFu - tt1);
    u64 K2 = ((u64)v2 << 32) | (u64)(0xFFFFFFFFu - tt2);
    // merge across the 4 lk-lanes of this lm-group
    u64 p0 = __shfl_xor(K0, 16), p1 = __shfl_xor(K1, 16), p2 = __shfl_xor(K2, 16);
    merge3(K0, K1, K2, p0, p1, p2);
    p0 = __shfl_xor(K0, 32); p1 = __shfl_xor(K1, 32); p2 = __shfl_xor(K2, 32);
    merge3(K0, K1, K2, p0, p1, p2);
    if (lk == 0) {
      int c = fn * 16 + lm;                  // 0..63
      ldsK[(wid * 64 + c) * 3 + 0] = K0;
      ldsK[(wid * 64 + c) * 3 + 1] = K1;
      ldsK[(wid * 64 + c) * 3 + 2] = K2;
    }
  }
  __syncthreads();
  if (wid < 2) {                             // wr==0 waves merge with their wr==1 partner
    int c = lane;                            // 0..63; e = e0 + wid*64 + c  (wid == wc here)
    u64 A0 = ldsK[(wid * 64 + c) * 3 + 0];
    u64 A1 = ldsK[(wid * 64 + c) * 3 + 1];
    u64 A2 = ldsK[(wid * 64 + c) * 3 + 2];
    u64 C0 = ldsK[((wid + 2) * 64 + c) * 3 + 0];
    u64 C1 = ldsK[((wid + 2) * 64 + c) * 3 + 1];
    u64 C2 = ldsK[((wid + 2) * 64 + c) * 3 + 2];
    merge3(A0, A1, A2, C0, C1, C2);
    int eg = e0 + wid * 64 + c;
    size_t R = (size_t)(mtile * 2 + b) * NE_ + (size_t)n * E_ + eg;
    k0g[R] = A0; k1g[R] = A1; k2g[R] = A2;
    // publish this tile's evaluated-subset 3rd-max as a prune threshold
    atomicMax(&thrbuf[(size_t)b * NE_ + (size_t)n * E_ + eg], (u32)(A2 >> 32));
  }
}

// ---------------- Kernel 3: merge tile records -> global top-3 -> slot scatter ----------------
__global__ __launch_bounds__(256) void merge_scatter2(const u64* __restrict__ k0g,
                                                      const u64* __restrict__ k1g,
                                                      const u64* __restrict__ k2g,
                                                      u64* __restrict__ keys) {
  int gid2 = blockIdx.x * 256 + threadIdx.x;  // 32768 = B*NB*E
  int b  = gid2 >> 14;
  int ne = gid2 & (NE_ - 1);

  u64 K0 = 0, K1 = 0, K2 = 0;
  for (int mt = 0; mt < MT_; ++mt) {
    size_t R = (size_t)(mt * 2 + b) * NE_ + ne;
    merge3(K0, K1, K2, k0g[R], k1g[R], k2g[R]);
  }

  int n = ne >> 12;
  u32 e = (u32)(ne & (E_ - 1));
  u64 elo = (u64)(0xFFFFFFFFu - e);
  u32 t0 = 0xFFFFFFFFu - (u32)K0;
  u32 t1 = 0xFFFFFFFFu - (u32)K1;
  u32 t2 = 0xFFFFFFFFu - (u32)K2;
  atomicMax(&keys[((size_t)b * T_ + t0) * NB_ + n], (K0 & 0xFFFFFFFF00000000ull) | elo);
  atomicMax(&keys[((size_t)b * T_ + t1) * NB_ + n], (K1 & 0xFFFFFFFF00000000ull) | elo);
  atomicMax(&keys[((size_t)b * T_ + t2) * NB_ + n], (K2 & 0xFFFFFFFF00000000ull) | elo);
}

// ---------------- Fallback path (small ws): in-kernel-split GEMM + monolithic select ----------------
__device__ __forceinline__ void split8(const float* __restrict__ p, f16x8 &hi, f16x8 &lo) {
  float4 a0 = *(const float4*)p;
  float4 a1 = *(const float4*)(p + 4);
  split8v(a0, a1, hi, lo);
}

__global__ __launch_bounds__(256) void gemm_logits_fb(const float* __restrict__ x,
                                                      const float* __restrict__ W,
                                                      float* __restrict__ logits) {
  __shared__ f16x8 AhV[128 * 4];
  __shared__ f16x8 AlV[128 * 4];
  __shared__ f16x8 BhV[128 * 4];
  __shared__ f16x8 BlV[128 * 4];

  const int n  = blockIdx.z;
  const int m0 = blockIdx.y * BM;
  const int e0 = blockIdx.x * BN;
  const int tid  = threadIdx.x;
  const int lane = tid & 63;
  const int wid  = tid >> 6;
  const int wr   = wid >> 1;
  const int wc   = wid & 1;
  const int lm   = lane & 15;
  const int lk   = lane >> 4;

  const float* Abase = x + ((size_t)m0 * NB_ + n) * D_;
  const float* Bbase = W + ((size_t)n * E_ + e0) * D_;

  f32x4 acc[4][4];
#pragma unroll
  for (int i = 0; i < 4; ++i)
#pragma unroll
    for (int j = 0; j < 4; ++j) acc[i][j] = (f32x4){0.f, 0.f, 0.f, 0.f};

  for (int k0 = 0; k0 < D_; k0 += 32) {
#pragma unroll
    for (int l = 0; l < 2; ++l) {
      int aid = tid + l * 256;
      int r   = aid >> 2;
      int ko  = aid & 3;
      int ps  = ko ^ ((r >> 1) & 3);
      f16x8 hi, lo;
      split8(Abase + (size_t)r * (NB_ * D_) + k0 + ko * 8, hi, lo);
      AhV[r * 4 + ps] = hi; AlV[r * 4 + ps] = lo;
      split8(Bbase + (size_t)r * D_ + k0 + ko * 8, hi, lo);
      BhV[r * 4 + ps] = hi; BlV[r * 4 + ps] = lo;
    }
    __syncthreads();

    f16x8 bh[4], bl[4];
#pragma unroll
    for (int fn = 0; fn < 4; ++fn) {
      int row = wc * 64 + fn * 16 + lm;
      int ps  = lk ^ ((row >> 1) & 3);
      bh[fn] = BhV[row * 4 + ps];
      bl[fn] = BlV[row * 4 + ps];
    }
#pragma unroll
    for (int fm = 0; fm < 4; ++fm) {
      int row = wr * 64 + fm * 16 + lm;
      int ps  = lk ^ ((row >> 1) & 3);
      f16x8 ah = AhV[row * 4 + ps];
      f16x8 al = AlV[row * 4 + ps];
#pragma unroll
      for (int fn = 0; fn < 4; ++fn) {
        acc[fm][fn] = __builtin_amdgcn_mfma_f32_16x16x32_f16(ah, bh[fn], acc[fm][fn], 0, 0, 0);
        acc[fm][fn] = __builtin_amdgcn_mfma_f32_16x16x32_f16(ah, bl[fn], acc[fm][fn], 0, 0, 0);
        acc[fm][fn] = __builtin_amdgcn_mfma_f32_16x16x32_f16(al, bh[fn], acc[fm][fn], 0, 0, 0);
      }
    }
    __syncthreads();
  }

#pragma unroll
  for (int fm = 0; fm < 4; ++fm) {
#pragma unroll
    for (int fn = 0; fn < 4; ++fn) {
#pragma unroll
      for (int r = 0; r < 4; ++r) {
        int m = m0 + wr * 64 + fm * 16 + lk * 4 + r;
        int e = e0 + wc * 64 + fn * 16 + lm;
        logits[((size_t)m * NB_ + n) * E_ + e] = acc[fm][fn][r] * INV_SC;
      }
    }
  }
}

__global__ __launch_bounds__(256) void select_scatter(const float* __restrict__ logits,
                                                      u64* __restrict__ keys) {
  int gid = blockIdx.x * 256 + threadIdx.x;  // 32768 = B*NB*E
  int b  = gid >> 14;
  int ne = gid & (NE_ - 1);

  float v0 = -1e30f, v1 = -1e30f, v2 = -1e30f;
  int   t0 = 0, t1 = 0, t2 = 0;

  const float* lg = logits + (size_t)b * HALF_;
  const u32 ib = (u32)b * HALF_ + (u32)ne;
  for (int t = 0; t < T_; ++t) {
    u32 i0 = (u32)t * (u32)NE_ + (u32)ne;
    float y = lg[i0] * noise_at(ib + (u32)t * (u32)NE_);
    if (y > v0)      { v2=v1; t2=t1; v1=v0; t1=t0; v0=y; t0=t; }
    else if (y > v1) { v2=v1; t2=t1; v1=y;  t1=t; }
    else if (y > v2) { v2=y;  t2=t; }
  }

  int n = ne >> 12;
  int e = ne & (E_ - 1);
  u64 klo = 0xFFFFFFFFull - (u32)e;
  atomicMax(&keys[((size_t)b * T_ + t0) * NB_ + n], ((u64)map_f32(v0) << 32) | klo);
  atomicMax(&keys[((size_t)b * T_ + t1) * NB_ + n], ((u64)map_f32(v1) << 32) | klo);
  atomicMax(&keys[((size_t)b * T_ + t2) * NB_ + n], ((u64)map_f32(v2) << 32) | klo);
}

// ---------------- Kernel 4: decode argmax -> idx + latent gather ----------------
__global__ __launch_bounds__(128) void finalize(const u64* __restrict__ keys,
                                                const float* __restrict__ W,
                                                float* __restrict__ out_idx,
                                                float* __restrict__ out_lat) {
  int slot = blockIdx.x;                     // (b*T+t)*NB + n
  int n = slot & (NB_ - 1);
  int e = (int)(0xFFFFFFFFu - (u32)keys[slot]) & (E_ - 1);
  if (threadIdx.x == 0) out_idx[slot] = (float)e;

  const float4 v = ((const float4*)(W + ((size_t)n * E_ + e) * D_))[threadIdx.x];
  ((float4*)(out_lat + (size_t)slot * D_))[threadIdx.x] = v;   // 128 x 16B = 2KB
}

// ---------------- Launch ----------------
extern "C" void kernel_launch(void* const* d_in, const int* in_sizes, int n_in,
                              void* d_out, int out_size, void* d_ws, size_t ws_size,
                              hipStream_t stream) {
  const float* x = (const float*)d_in[0];    // [B,T,NB*D] fp32
  const float* W = (const float*)d_in[1];    // [NB,E,D]  fp32

  float* out_idx    = (float*)d_out;                          // 32,768
  float* out_lat    = out_idx + (size_t)SLOTS_;               // 16,777,216
  float* out_logits = out_lat + (size_t)SLOTS_ * D_;          // 134,217,728

  // ws layout: keys | thr | xh | xl | wh | wl
  u64* keys = (u64*)d_ws;
  const size_t KEYS_B = (size_t)SLOTS_ * 8;                   // 256 KiB
  const size_t THR_B  = (size_t)SLOTS_ * 4;                   // 128 KiB
  const size_t XH_B   = (size_t)XN8_ * 16;                    // 32 MiB
  const size_t WH_B   = (size_t)WN8_ * 16;                    // 16 MiB
  bool split = ws_size >= KEYS_B + THR_B + 2 * XH_B + 2 * WH_B;

  u32*   thr = (u32*)((char*)d_ws + KEYS_B);
  char*  sp  = (char*)d_ws + KEYS_B + THR_B;
  f16x8* xh  = (f16x8*)sp;
  f16x8* xl  = (f16x8*)(sp + XH_B);
  f16x8* wh  = (f16x8*)(sp + 2 * XH_B);
  f16x8* wl  = (f16x8*)(sp + 2 * XH_B + WH_B);

  // tile-select records live in the out_lat region (overwritten by finalize later)
  u64* k0g = (u64*)out_lat;                                   // 8 MB each
  u64* k1g = k0g + RECN_;
  u64* k2g = k1g + RECN_;

  init_keys<<<SLOTS_ / 256, 256, 0, stream>>>(keys, thr);

  if (split) {
    presplit<<<(XN8_ + WN8_) / 256, 256, 0, stream>>>(x, W, xh, xl, wh, wl);
    gemm_fused<<<8192, 256, 0, stream>>>(xh, xl, wh, wl, out_logits, k0g, k1g, k2g, thr);
    merge_scatter2<<<SLOTS_ / 256, 256, 0, stream>>>(k0g, k1g, k2g, keys);
  } else {
    dim3 ggrid(E_ / BN, (B_ * T_) / BM, NB_);
    gemm_logits_fb<<<ggrid, 256, 0, stream>>>(x, W, out_logits);
    select_scatter<<<SLOTS_ / 256, 256, 0, stream>>>(out_logits, keys);
  }

  finalize<<<SLOTS_, 128, 0, stream>>>(keys, W, out_idx, out_lat);
}